// Round 3
// baseline (650.067 us; speedup 1.0000x reference)
//
#include <hip/hip_runtime.h>
#include <hip/hip_bf16.h>
#include <math.h>

#define Bb 8
#define Tt 512
#define Cc 512
#define Hh 8
#define HKV 4
#define Dd 64

__device__ __forceinline__ float wave_reduce_max(float v) {
#pragma unroll
  for (int off = 32; off > 0; off >>= 1) v = fmaxf(v, __shfl_xor(v, off, 64));
  return v;
}
__device__ __forceinline__ float wave_reduce_sum(float v) {
#pragma unroll
  for (int off = 32; off > 0; off >>= 1) v += __shfl_xor(v, off, 64);
  return v;
}

__device__ __forceinline__ unsigned pack_bf2(float a, float b) {
  __hip_bfloat162 h = __float22bfloat162_rn(make_float2(a, b));
  return *(unsigned*)&h;
}
__device__ __forceinline__ float2 bf2(unsigned u) {
  return make_float2(__uint_as_float(u << 16), __uint_as_float(u & 0xffff0000u));
}

// ---------------- QKV GEMM: x(4096x512) @ [Wq|Wk|Wv] -> q,k,v ----------------
__global__ __launch_bounds__(256) void qkv_gemm(
    const float* __restrict__ x, const float* __restrict__ Wq,
    const float* __restrict__ Wk, const float* __restrict__ Wv,
    float* __restrict__ q, float* __restrict__ k, float* __restrict__ v) {
  __shared__ float As[64][20];
  __shared__ float Bs[16][68];
  const int m0 = blockIdx.x * 64;
  const int n0 = blockIdx.y * 64;
  const float* Wsrc;
  int ldw, noff;
  if (n0 < 512)      { Wsrc = Wq; ldw = 512; noff = n0; }
  else if (n0 < 768) { Wsrc = Wk; ldw = 256; noff = n0 - 512; }
  else               { Wsrc = Wv; ldw = 256; noff = n0 - 768; }
  const int t = threadIdx.x;
  const int tx = t & 15, ty = t >> 4;
  const int am = t >> 2, ak = (t & 3) << 2;
  const int bk = t >> 4, bn = (t & 15) << 2;
  float acc[4][4] = {};
  for (int k0 = 0; k0 < Cc; k0 += 16) {
    float4 a4 = *(const float4*)&x[(m0 + am) * Cc + k0 + ak];
    float4 b4 = *(const float4*)&Wsrc[(k0 + bk) * ldw + noff + bn];
    *(float4*)&As[am][ak] = a4;
    *(float4*)&Bs[bk][bn] = b4;
    __syncthreads();
#pragma unroll
    for (int kk = 0; kk < 16; ++kk) {
      float4 b = *(float4*)&Bs[kk][tx << 2];
#pragma unroll
      for (int i = 0; i < 4; ++i) {
        float a = As[(ty << 2) + i][kk];
        acc[i][0] = fmaf(a, b.x, acc[i][0]);
        acc[i][1] = fmaf(a, b.y, acc[i][1]);
        acc[i][2] = fmaf(a, b.z, acc[i][2]);
        acc[i][3] = fmaf(a, b.w, acc[i][3]);
      }
    }
    __syncthreads();
  }
#pragma unroll
  for (int i = 0; i < 4; ++i) {
    int m = m0 + (ty << 2) + i;
    float4 val = make_float4(acc[i][0], acc[i][1], acc[i][2], acc[i][3]);
    if (n0 < 512)      *(float4*)&q[m * 512 + n0 + (tx << 2)] = val;
    else if (n0 < 768) *(float4*)&k[m * 256 + (n0 - 512) + (tx << 2)] = val;
    else               *(float4*)&v[m * 256 + (n0 - 768) + (tx << 2)] = val;
  }
}

// ---------------- Proj GEMM: y(4096x512) @ Wproj(512x512) -> out ----------------
__global__ __launch_bounds__(256) void proj_gemm(
    const float* __restrict__ A, const float* __restrict__ W,
    float* __restrict__ out) {
  __shared__ float As[64][20];
  __shared__ float Bs[16][68];
  const int m0 = blockIdx.x * 64;
  const int n0 = blockIdx.y * 64;
  const int t = threadIdx.x;
  const int tx = t & 15, ty = t >> 4;
  const int am = t >> 2, ak = (t & 3) << 2;
  const int bk = t >> 4, bn = (t & 15) << 2;
  float acc[4][4] = {};
  for (int k0 = 0; k0 < Cc; k0 += 16) {
    float4 a4 = *(const float4*)&A[(m0 + am) * Cc + k0 + ak];
    float4 b4 = *(const float4*)&W[(k0 + bk) * 512 + n0 + bn];
    *(float4*)&As[am][ak] = a4;
    *(float4*)&Bs[bk][bn] = b4;
    __syncthreads();
#pragma unroll
    for (int kk = 0; kk < 16; ++kk) {
      float4 b = *(float4*)&Bs[kk][tx << 2];
#pragma unroll
      for (int i = 0; i < 4; ++i) {
        float a = As[(ty << 2) + i][kk];
        acc[i][0] = fmaf(a, b.x, acc[i][0]);
        acc[i][1] = fmaf(a, b.y, acc[i][1]);
        acc[i][2] = fmaf(a, b.z, acc[i][2]);
        acc[i][3] = fmaf(a, b.w, acc[i][3]);
      }
    }
    __syncthreads();
  }
#pragma unroll
  for (int i = 0; i < 4; ++i) {
    int m = m0 + (ty << 2) + i;
    *(float4*)&out[m * 512 + n0 + (tx << 2)] =
        make_float4(acc[i][0], acc[i][1], acc[i][2], acc[i][3]);
  }
}

// ---------------- RMS-norm of q and k rows (64-wide) ----------------
__global__ __launch_bounds__(256) void norm_qk(float* __restrict__ q,
                                               float* __restrict__ k) {
  int w = blockIdx.x * 4 + (threadIdx.x >> 6);
  int lane = threadIdx.x & 63;
  float* row = (w < Bb * Tt * Hh) ? (q + w * 64) : (k + (w - Bb * Tt * Hh) * 64);
  float val = row[lane];
  float ss = wave_reduce_sum(val * val);
  row[lane] = val * 8.0f * rsqrtf(ss + 1e-6f);
}

// ---------------- Pw[h][delta+511][d] table ----------------
__global__ __launch_bounds__(256) void build_pw(const float* __restrict__ P,
                                                const float* __restrict__ sigma,
                                                float* __restrict__ Pw) {
  int idx = blockIdx.x * blockDim.x + threadIdx.x;
  if (idx >= Hh * 1023 * 64) return;
  int d = idx & 63;
  int rem = idx >> 6;
  int dd = rem % 1023;
  int h = rem / 1023;
  float s = fabsf(sigma[h]) + 1e-6f;
  float delta = (float)(dd - 511);
  float dt = 128.0f * tanhf(delta / s) + 128.0f;
  float lo = floorf(dt);
  int ilo = (int)lo;
  float frac = dt - lo;
  ilo = max(0, min(ilo, 256));
  int ihi = min(ilo + 1, 256);
  const float* Pb = P + h * 257 * 64;
  Pw[idx] = (1.0f - frac) * Pb[ilo * 64 + d] + frac * Pb[ihi * 64 + d];
}

// ---------------- Attention v3: bf16-LDS flash-style ----------------
// grid (T/16, B*H), block 256 (4 waves x 4 rows each)
// LDS (bf16 tiles): KsH 9KB + PwH 11.25KB + qH 2.25KB + pS 4KB = 26.5KB
//   -> ~5-6 blocks/CU by LDS (was 1 block at 65KB fp32).
// Score phase reads 8-dim chunks per b128 (was 4) -> 72 LDS reads/wave-tile (was 144).
// V read direct from global (coalesced, L1-served) -> off the LDS pipe.
// No per-lane register arrays (round-2 spill lesson).
__global__ __launch_bounds__(256) void attn(
    const float* __restrict__ q, const float* __restrict__ k,
    const float* __restrict__ v, const float* __restrict__ Pw,
    float* __restrict__ y) {
  __shared__ __align__(16) unsigned short KsH[64][72];
  __shared__ __align__(16) unsigned short PwH[80][72];
  __shared__ __align__(16) unsigned short qH[16][72];
  __shared__ float pS[4][64][4];

  const int t = threadIdx.x;
  const int w = t >> 6;
  const int lane = t & 63;
  const int bh = blockIdx.y;
  const int b = bh >> 3;
  const int h = bh & 7;
  const int hkv = h >> 1;
  const int i0 = blockIdx.x * 16;

  // stage q tile as bf16: thread t handles row t>>4, 4 elems at (t&15)*4
  {
    int row = t >> 4, dc = (t & 15) << 2;
    float4 qv = *(const float4*)&q[((b * Tt + i0 + row) * Hh + h) * Dd + dc];
    unsigned u0 = pack_bf2(qv.x, qv.y);
    unsigned u1 = pack_bf2(qv.z, qv.w);
    *(uint2*)&qH[row][dc] = make_uint2(u0, u1);
  }

  float m_run[4], l_run[4], o_run[4];
#pragma unroll
  for (int r = 0; r < 4; ++r) { m_run[r] = -1e30f; l_run[r] = 0.0f; o_run[r] = 0.0f; }

  const int i_base = i0 + (w << 2);
  const int i_max_blk = i0 + 15;

  for (int jt0 = 0; jt0 <= i_max_blk; jt0 += 64) {
    __syncthreads();
    {
      // thread t: row jr = t>>2, 16 elems at (t&3)*16
      int jr = t >> 2, dc = (t & 3) << 4;
      const float* kp = &k[((b * Tt + jt0 + jr) * HKV + hkv) * Dd + dc];
      unsigned ku[8];
#pragma unroll
      for (int c = 0; c < 4; ++c) {
        float4 f = *(const float4*)&kp[c * 4];
        ku[c * 2]     = pack_bf2(f.x, f.y);
        ku[c * 2 + 1] = pack_bf2(f.z, f.w);
      }
      *(uint4*)&KsH[jr][dc]     = *(uint4*)&ku[0];
      *(uint4*)&KsH[jr][dc + 8] = *(uint4*)&ku[4];

      const int ddbase = i0 - jt0 + 448;  // Pw table row for PwH row 0
      const float* pwp = &Pw[(h * 1023 + (jr + ddbase)) * 64 + dc];
#pragma unroll
      for (int c = 0; c < 4; ++c) {
        float4 f = *(const float4*)&pwp[c * 4];
        ku[c * 2]     = pack_bf2(f.x, f.y);
        ku[c * 2 + 1] = pack_bf2(f.z, f.w);
      }
      *(uint4*)&PwH[jr][dc]     = *(uint4*)&ku[0];
      *(uint4*)&PwH[jr][dc + 8] = *(uint4*)&ku[4];
      int pr2 = jr + 64;
      if (pr2 < 79) {
        const float* pwp2 = &Pw[(h * 1023 + (pr2 + ddbase)) * 64 + dc];
#pragma unroll
        for (int c = 0; c < 4; ++c) {
          float4 f = *(const float4*)&pwp2[c * 4];
          ku[c * 2]     = pack_bf2(f.x, f.y);
          ku[c * 2 + 1] = pack_bf2(f.z, f.w);
        }
        *(uint4*)&PwH[pr2][dc]     = *(uint4*)&ku[0];
        *(uint4*)&PwH[pr2][dc + 8] = *(uint4*)&ku[4];
      }
    }
    __syncthreads();

    // score phase: lane = j, 8-dim chunks
    float s[4] = {0.0f, 0.0f, 0.0f, 0.0f};
#pragma unroll
    for (int ch = 0; ch < 8; ++ch) {
      const int dc = ch << 3;
      uint4 ku4 = *(uint4*)&KsH[lane][dc];
      float2 k0 = bf2(ku4.x), k1 = bf2(ku4.y), k2 = bf2(ku4.z), k3 = bf2(ku4.w);
#pragma unroll
      for (int r = 0; r < 4; ++r) {
        uint4 qu4 = *(uint4*)&qH[(w << 2) + r][dc];
        uint4 pu4 = *(uint4*)&PwH[(w << 2) + r + 63 - lane][dc];
        float2 q0 = bf2(qu4.x), q1 = bf2(qu4.y), q2 = bf2(qu4.z), q3 = bf2(qu4.w);
        float2 p0 = bf2(pu4.x), p1 = bf2(pu4.y), p2 = bf2(pu4.z), p3 = bf2(pu4.w);
        s[r] = fmaf(q0.x * p0.x, k0.x, s[r]);
        s[r] = fmaf(q0.y * p0.y, k0.y, s[r]);
        s[r] = fmaf(q1.x * p1.x, k1.x, s[r]);
        s[r] = fmaf(q1.y * p1.y, k1.y, s[r]);
        s[r] = fmaf(q2.x * p2.x, k2.x, s[r]);
        s[r] = fmaf(q2.y * p2.y, k2.y, s[r]);
        s[r] = fmaf(q3.x * p3.x, k3.x, s[r]);
        s[r] = fmaf(q3.y * p3.y, k3.y, s[r]);
      }
    }
    int j = jt0 + lane;
    float pv[4];
#pragma unroll
    for (int r = 0; r < 4; ++r) {
      int i_r = i_base + r;
      float p = 0.0f;
      if (jt0 <= i_r) {
        float sv = (j <= i_r) ? s[r] * 0.125f : -1e30f;
        float mnew = fmaxf(m_run[r], wave_reduce_max(sv));
        p = __expf(sv - mnew);
        float alpha = __expf(m_run[r] - mnew);
        l_run[r] = l_run[r] * alpha + wave_reduce_sum(p);
        o_run[r] *= alpha;
        m_run[r] = mnew;
      }
      pv[r] = p;
    }
    *(float4*)&pS[w][lane][0] = make_float4(pv[0], pv[1], pv[2], pv[3]);

    // PV phase: lane = d; V direct from global (coalesced b32, L1-hot)
    const float* vp = &v[((b * Tt + jt0) * HKV + hkv) * Dd + lane];
#pragma unroll 8
    for (int jj = 0; jj < 64; ++jj) {
      float4 p4 = *(float4*)&pS[w][jj][0];  // broadcast read
      float vv = vp[jj * (HKV * Dd)];
      o_run[0] = fmaf(p4.x, vv, o_run[0]);
      o_run[1] = fmaf(p4.y, vv, o_run[1]);
      o_run[2] = fmaf(p4.z, vv, o_run[2]);
      o_run[3] = fmaf(p4.w, vv, o_run[3]);
    }
  }
#pragma unroll
  for (int r = 0; r < 4; ++r) {
    int i_r = i_base + r;
    y[((b * Tt + i_r) * Hh + h) * Dd + lane] = o_run[r] / l_run[r];
  }
}

extern "C" void kernel_launch(void* const* d_in, const int* in_sizes, int n_in,
                              void* d_out, int out_size, void* d_ws, size_t ws_size,
                              hipStream_t stream) {
  const float* x     = (const float*)d_in[0];
  const float* Wq    = (const float*)d_in[1];
  const float* Wk    = (const float*)d_in[2];
  const float* Wv    = (const float*)d_in[3];
  const float* Wproj = (const float*)d_in[4];
  const float* P     = (const float*)d_in[5];
  const float* sigma = (const float*)d_in[6];
  float* out = (float*)d_out;

  float* ws = (float*)d_ws;
  float* q  = ws;                     // 2097152
  float* k  = q + 2097152;            // 1048576
  float* v  = k + 1048576;            // 1048576
  float* Pw = v + 1048576;            // 523776
  float* y  = Pw + 523776;            // 2097152

  qkv_gemm<<<dim3(64, 16), 256, 0, stream>>>(x, Wq, Wk, Wv, q, k, v);
  norm_qk<<<dim3(12288), 256, 0, stream>>>(q, k);
  build_pw<<<dim3(2046), 256, 0, stream>>>(P, sigma, Pw);
  attn<<<dim3(32, 64), 256, 0, stream>>>(q, k, v, Pw, y);
  proj_gemm<<<dim3(64, 8), 256, 0, stream>>>(y, Wproj, out);
}

// Round 4
// 317.678 us; speedup vs baseline: 2.0463x; 2.0463x over previous
//
#include <hip/hip_runtime.h>
#include <hip/hip_bf16.h>
#include <math.h>

#define Bb 8
#define Tt 512
#define Cc 512
#define Hh 8
#define HKV 4
#define Dd 64

typedef __attribute__((ext_vector_type(8))) short short8;
typedef __attribute__((ext_vector_type(4))) float float4v;

__device__ __forceinline__ float wave_reduce_max(float v) {
#pragma unroll
  for (int off = 32; off > 0; off >>= 1) v = fmaxf(v, __shfl_xor(v, off, 64));
  return v;
}
__device__ __forceinline__ float wave_reduce_sum(float v) {
#pragma unroll
  for (int off = 32; off > 0; off >>= 1) v += __shfl_xor(v, off, 64);
  return v;
}
__device__ __forceinline__ unsigned pack_bf2(float a, float b) {
  __hip_bfloat162 h = __float22bfloat162_rn(make_float2(a, b));
  return *(unsigned*)&h;
}

// ---------------- x fp32 -> bf16 ----------------
__global__ __launch_bounds__(256) void conv_x(const float* __restrict__ x,
                                              unsigned short* __restrict__ xb) {
  int i = (blockIdx.x * 256 + threadIdx.x) * 8;
  float4 f0 = *(const float4*)&x[i];
  float4 f1 = *(const float4*)&x[i + 4];
  unsigned u[4] = {pack_bf2(f0.x, f0.y), pack_bf2(f0.z, f0.w),
                   pack_bf2(f1.x, f1.y), pack_bf2(f1.z, f1.w)};
  *(uint4*)&xb[i] = *(uint4*)u;
}

// ---------------- W transpose+convert: Wt[n][k] bf16 ----------------
// grid (K/64=8, 24): n0<512 Wq | <768 Wk | <1024 Wv -> Wtq ; else Wproj -> Wtp
__global__ __launch_bounds__(256) void conv_w(
    const float* __restrict__ Wq, const float* __restrict__ Wk,
    const float* __restrict__ Wv, const float* __restrict__ Wp,
    unsigned short* __restrict__ Wtq, unsigned short* __restrict__ Wtp) {
  __shared__ float Ts[64][65];
  const int k0 = blockIdx.x * 64;
  const int n0 = blockIdx.y * 64;
  const float* src; int ld, nc0; unsigned short* dst; int ndst;
  if (n0 < 512)       { src = Wq; ld = 512; nc0 = n0;        dst = Wtq; ndst = n0; }
  else if (n0 < 768)  { src = Wk; ld = 256; nc0 = n0 - 512;  dst = Wtq; ndst = n0; }
  else if (n0 < 1024) { src = Wv; ld = 256; nc0 = n0 - 768;  dst = Wtq; ndst = n0; }
  else                { src = Wp; ld = 512; nc0 = n0 - 1024; dst = Wtp; ndst = n0 - 1024; }
  const int t = threadIdx.x;
  const int r = t >> 4, c4 = (t & 15) << 2;
#pragma unroll
  for (int rr = 0; rr < 4; ++rr) {
    int row = (rr << 4) + r;
    float4 f = *(const float4*)&src[(k0 + row) * ld + nc0 + c4];
    Ts[row][c4] = f.x; Ts[row][c4 + 1] = f.y;
    Ts[row][c4 + 2] = f.z; Ts[row][c4 + 3] = f.w;
  }
  __syncthreads();
#pragma unroll
  for (int rr = 0; rr < 4; ++rr) {
    int nr = (rr << 4) + r;
    unsigned u0 = pack_bf2(Ts[c4][nr], Ts[c4 + 1][nr]);
    unsigned u1 = pack_bf2(Ts[c4 + 2][nr], Ts[c4 + 3][nr]);
    *(uint2*)&dst[(ndst + nr) * 512 + k0 + c4] = make_uint2(u0, u1);
  }
}

// ---------------- QKV MFMA GEMM: xb(4096x512) @ Wtq^T -> q,k,v fp32 ----------------
// 64x64 tile/block, 4 waves (wave w: rows w*16..+15, all 64 cols), BK=64.
// LDS rows 64 bf16 = 128B unpadded (m97-proven layout).
__global__ __launch_bounds__(256) void qkv_mfma(
    const unsigned short* __restrict__ xb, const unsigned short* __restrict__ Wt,
    float* __restrict__ q, float* __restrict__ k, float* __restrict__ v) {
  __shared__ unsigned short As[64][64];
  __shared__ unsigned short Bs[64][64];
  const int m0 = blockIdx.x * 64;
  const int n0 = blockIdx.y * 64;
  const int t = threadIdx.x;
  const int w = t >> 6, lane = t & 63;
  const int srow = t >> 2, sc = (t & 3) << 4;
  float4v acc[4] = {{0,0,0,0},{0,0,0,0},{0,0,0,0},{0,0,0,0}};
  for (int k0 = 0; k0 < 512; k0 += 64) {
    uint4 a0 = *(const uint4*)&xb[(m0 + srow) * 512 + k0 + sc];
    uint4 a1 = *(const uint4*)&xb[(m0 + srow) * 512 + k0 + sc + 8];
    uint4 b0 = *(const uint4*)&Wt[(n0 + srow) * 512 + k0 + sc];
    uint4 b1 = *(const uint4*)&Wt[(n0 + srow) * 512 + k0 + sc + 8];
    __syncthreads();
    *(uint4*)&As[srow][sc] = a0; *(uint4*)&As[srow][sc + 8] = a1;
    *(uint4*)&Bs[srow][sc] = b0; *(uint4*)&Bs[srow][sc + 8] = b1;
    __syncthreads();
    const int ml = (w << 4) + (lane & 15);
    const int kq = (lane >> 4) << 3;
    short8 aF0 = *(short8*)&As[ml][kq];
    short8 aF1 = *(short8*)&As[ml][kq + 32];
#pragma unroll
    for (int nt = 0; nt < 4; ++nt) {
      const int nl = (nt << 4) + (lane & 15);
      short8 bF0 = *(short8*)&Bs[nl][kq];
      short8 bF1 = *(short8*)&Bs[nl][kq + 32];
      acc[nt] = __builtin_amdgcn_mfma_f32_16x16x32_bf16(aF0, bF0, acc[nt], 0, 0, 0);
      acc[nt] = __builtin_amdgcn_mfma_f32_16x16x32_bf16(aF1, bF1, acc[nt], 0, 0, 0);
    }
  }
#pragma unroll
  for (int nt = 0; nt < 4; ++nt) {
    int col = n0 + (nt << 4) + (lane & 15);
#pragma unroll
    for (int r = 0; r < 4; ++r) {
      int row = m0 + (w << 4) + ((lane >> 4) << 2) + r;
      float val = acc[nt][r];
      if (col < 512)      q[row * 512 + col] = val;
      else if (col < 768) k[row * 256 + (col - 512)] = val;
      else                v[row * 256 + (col - 768)] = val;
    }
  }
}

// ---------------- Proj MFMA GEMM: yb(4096x512) @ Wtp^T -> out fp32 ----------------
__global__ __launch_bounds__(256) void proj_mfma(
    const unsigned short* __restrict__ yb, const unsigned short* __restrict__ Wt,
    float* __restrict__ out) {
  __shared__ unsigned short As[64][64];
  __shared__ unsigned short Bs[64][64];
  const int m0 = blockIdx.x * 64;
  const int n0 = blockIdx.y * 64;
  const int t = threadIdx.x;
  const int w = t >> 6, lane = t & 63;
  const int srow = t >> 2, sc = (t & 3) << 4;
  float4v acc[4] = {{0,0,0,0},{0,0,0,0},{0,0,0,0},{0,0,0,0}};
  for (int k0 = 0; k0 < 512; k0 += 64) {
    uint4 a0 = *(const uint4*)&yb[(m0 + srow) * 512 + k0 + sc];
    uint4 a1 = *(const uint4*)&yb[(m0 + srow) * 512 + k0 + sc + 8];
    uint4 b0 = *(const uint4*)&Wt[(n0 + srow) * 512 + k0 + sc];
    uint4 b1 = *(const uint4*)&Wt[(n0 + srow) * 512 + k0 + sc + 8];
    __syncthreads();
    *(uint4*)&As[srow][sc] = a0; *(uint4*)&As[srow][sc + 8] = a1;
    *(uint4*)&Bs[srow][sc] = b0; *(uint4*)&Bs[srow][sc + 8] = b1;
    __syncthreads();
    const int ml = (w << 4) + (lane & 15);
    const int kq = (lane >> 4) << 3;
    short8 aF0 = *(short8*)&As[ml][kq];
    short8 aF1 = *(short8*)&As[ml][kq + 32];
#pragma unroll
    for (int nt = 0; nt < 4; ++nt) {
      const int nl = (nt << 4) + (lane & 15);
      short8 bF0 = *(short8*)&Bs[nl][kq];
      short8 bF1 = *(short8*)&Bs[nl][kq + 32];
      acc[nt] = __builtin_amdgcn_mfma_f32_16x16x32_bf16(aF0, bF0, acc[nt], 0, 0, 0);
      acc[nt] = __builtin_amdgcn_mfma_f32_16x16x32_bf16(aF1, bF1, acc[nt], 0, 0, 0);
    }
  }
#pragma unroll
  for (int nt = 0; nt < 4; ++nt) {
    int col = n0 + (nt << 4) + (lane & 15);
#pragma unroll
    for (int r = 0; r < 4; ++r) {
      int row = m0 + (w << 4) + ((lane >> 4) << 2) + r;
      out[row * 512 + col] = acc[nt][r];
    }
  }
}

// ---------------- RMS-norm of q and k rows (64-wide) ----------------
__global__ __launch_bounds__(256) void norm_qk(float* __restrict__ q,
                                               float* __restrict__ k) {
  int w = blockIdx.x * 4 + (threadIdx.x >> 6);
  int lane = threadIdx.x & 63;
  float* row = (w < Bb * Tt * Hh) ? (q + w * 64) : (k + (w - Bb * Tt * Hh) * 64);
  float val = row[lane];
  float ss = wave_reduce_sum(val * val);
  row[lane] = val * 8.0f * rsqrtf(ss + 1e-6f);
}

// ---------------- Pw[h][delta+511][d] table ----------------
__global__ __launch_bounds__(256) void build_pw(const float* __restrict__ P,
                                                const float* __restrict__ sigma,
                                                float* __restrict__ Pw) {
  int idx = blockIdx.x * blockDim.x + threadIdx.x;
  if (idx >= Hh * 1023 * 64) return;
  int d = idx & 63;
  int rem = idx >> 6;
  int dd = rem % 1023;
  int h = rem / 1023;
  float s = fabsf(sigma[h]) + 1e-6f;
  float delta = (float)(dd - 511);
  float dt = 128.0f * tanhf(delta / s) + 128.0f;
  float lo = floorf(dt);
  int ilo = (int)lo;
  float frac = dt - lo;
  ilo = max(0, min(ilo, 256));
  int ihi = min(ilo + 1, 256);
  const float* Pb = P + h * 257 * 64;
  Pw[idx] = (1.0f - frac) * Pb[ilo * 64 + d] + frac * Pb[ihi * 64 + d];
}

// ---------------- Attention v4: fp32 flash, no V tile ----------------
// LDS: Ks 17.4K + PwS 21.8K + qS 4.3K + pS 4K = 47.6KB -> 3 blocks/CU.
// V coalesced from global (L1/L2-hot). pS: one conflict-free float4/lane.
// Output written as bf16 (feeds proj_mfma directly).
__global__ __launch_bounds__(256) void attn(
    const float* __restrict__ q, const float* __restrict__ k,
    const float* __restrict__ v, const float* __restrict__ Pw,
    unsigned short* __restrict__ yb) {
  __shared__ float Ks[64][68];
  __shared__ float PwS[80][68];
  __shared__ float qS[16][68];
  __shared__ float pS[4][64][4];

  const int t = threadIdx.x;
  const int w = t >> 6;
  const int lane = t & 63;
  const int bh = blockIdx.y;
  const int b = bh >> 3;
  const int h = bh & 7;
  const int hkv = h >> 1;
  const int i0 = blockIdx.x * 16;

  {
    int row = t >> 4, dc = (t & 15) << 2;
    *(float4*)&qS[row][dc] =
        *(const float4*)&q[((b * Tt + i0 + row) * Hh + h) * Dd + dc];
  }

  float m_run[4], l_run[4], o_run[4];
#pragma unroll
  for (int r = 0; r < 4; ++r) { m_run[r] = -1e30f; l_run[r] = 0.0f; o_run[r] = 0.0f; }

  const int i_base = i0 + (w << 2);
  const int i_max_blk = i0 + 15;

  for (int jt0 = 0; jt0 <= i_max_blk; jt0 += 64) {
    __syncthreads();
    {
      int jr = t >> 2, dc = (t & 3) << 4;
      const float* kp = &k[((b * Tt + jt0 + jr) * HKV + hkv) * Dd + dc];
#pragma unroll
      for (int c = 0; c < 4; ++c)
        *(float4*)&Ks[jr][dc + c * 4] = *(const float4*)&kp[c * 4];
      const int ddbase = i0 - jt0 + 448;
      const float* pwp = &Pw[(h * 1023 + (jr + ddbase)) * 64 + dc];
#pragma unroll
      for (int c = 0; c < 4; ++c)
        *(float4*)&PwS[jr][dc + c * 4] = *(const float4*)&pwp[c * 4];
      int pr2 = jr + 64;
      if (pr2 < 79) {
        const float* pwp2 = &Pw[(h * 1023 + (pr2 + ddbase)) * 64 + dc];
#pragma unroll
        for (int c = 0; c < 4; ++c)
          *(float4*)&PwS[pr2][dc + c * 4] = *(const float4*)&pwp2[c * 4];
      }
    }
    __syncthreads();

    // score phase: lane = j
    float s[4] = {0.0f, 0.0f, 0.0f, 0.0f};
#pragma unroll 4
    for (int dc = 0; dc < 64; dc += 4) {
      float4 kk4 = *(float4*)&Ks[lane][dc];
#pragma unroll
      for (int r = 0; r < 4; ++r) {
        float4 q4 = *(float4*)&qS[(w << 2) + r][dc];
        float4 p4 = *(float4*)&PwS[(w << 2) + r + 63 - lane][dc];
        s[r] = fmaf(q4.x * p4.x, kk4.x, s[r]);
        s[r] = fmaf(q4.y * p4.y, kk4.y, s[r]);
        s[r] = fmaf(q4.z * p4.z, kk4.z, s[r]);
        s[r] = fmaf(q4.w * p4.w, kk4.w, s[r]);
      }
    }
    int j = jt0 + lane;
    float pv[4];
#pragma unroll
    for (int r = 0; r < 4; ++r) {
      int i_r = i_base + r;
      float p = 0.0f;
      if (jt0 <= i_r) {
        float sv = (j <= i_r) ? s[r] * 0.125f : -1e30f;
        float mnew = fmaxf(m_run[r], wave_reduce_max(sv));
        p = __expf(sv - mnew);
        float alpha = __expf(m_run[r] - mnew);
        l_run[r] = l_run[r] * alpha + wave_reduce_sum(p);
        o_run[r] *= alpha;
        m_run[r] = mnew;
      }
      pv[r] = p;
    }
    *(float4*)&pS[w][lane][0] = make_float4(pv[0], pv[1], pv[2], pv[3]);

    // PV phase: lane = d; V direct from global (coalesced, L1/L2-hot)
    const float* vp = &v[((b * Tt + jt0) * HKV + hkv) * Dd + lane];
#pragma unroll 8
    for (int jj = 0; jj < 64; ++jj) {
      float4 p4 = *(float4*)&pS[w][jj][0];  // broadcast read
      float vv = vp[jj * (HKV * Dd)];
      o_run[0] = fmaf(p4.x, vv, o_run[0]);
      o_run[1] = fmaf(p4.y, vv, o_run[1]);
      o_run[2] = fmaf(p4.z, vv, o_run[2]);
      o_run[3] = fmaf(p4.w, vv, o_run[3]);
    }
  }
#pragma unroll
  for (int r = 0; r < 4; ++r) {
    int i_r = i_base + r;
    __hip_bfloat16 hv = __float2bfloat16(o_run[r] / l_run[r]);
    yb[((b * Tt + i_r) * Hh + h) * Dd + lane] = *(unsigned short*)&hv;
  }
}

extern "C" void kernel_launch(void* const* d_in, const int* in_sizes, int n_in,
                              void* d_out, int out_size, void* d_ws, size_t ws_size,
                              hipStream_t stream) {
  const float* x     = (const float*)d_in[0];
  const float* Wq    = (const float*)d_in[1];
  const float* Wk    = (const float*)d_in[2];
  const float* Wv    = (const float*)d_in[3];
  const float* Wproj = (const float*)d_in[4];
  const float* P     = (const float*)d_in[5];
  const float* sigma = (const float*)d_in[6];
  float* out = (float*)d_out;

  float* ws = (float*)d_ws;
  float* q  = ws;                              // 2,097,152 f
  float* k  = q + 2097152;                     // 1,048,576 f
  float* v  = k + 1048576;                     // 1,048,576 f
  float* Pw = v + 1048576;                     // 523,776 f (pad to 524,288)
  unsigned short* xb  = (unsigned short*)(ws + 4718592);  // 2M bf16 (= 1M f)
  unsigned short* yb  = xb;                               // aliased: xb dead after qkv_mfma
  unsigned short* Wtq = (unsigned short*)(ws + 5767168);  // 512K bf16
  unsigned short* Wtp = (unsigned short*)(ws + 6029312);  // 256K bf16
  // total: 6,160,384 floats = 24.6 MB (< 26.1 MB proven in earlier rounds)

  conv_x<<<dim3(1024), 256, 0, stream>>>(x, xb);
  conv_w<<<dim3(8, 24), 256, 0, stream>>>(Wq, Wk, Wv, Wproj, Wtq, Wtp);
  qkv_mfma<<<dim3(64, 16), 256, 0, stream>>>(xb, Wtq, q, k, v);
  norm_qk<<<dim3(12288), 256, 0, stream>>>(q, k);
  build_pw<<<dim3(2046), 256, 0, stream>>>(P, sigma, Pw);
  attn<<<dim3(32, 64), 256, 0, stream>>>(q, k, v, Pw, yb);
  proj_mfma<<<dim3(64, 8), 256, 0, stream>>>(yb, Wtp, out);
}

// Round 5
// 298.060 us; speedup vs baseline: 2.1810x; 1.0658x over previous
//
#include <hip/hip_runtime.h>
#include <hip/hip_bf16.h>
#include <math.h>

#define Bb 8
#define Tt 512
#define Cc 512
#define Hh 8
#define HKV 4
#define Dd 64

typedef __attribute__((ext_vector_type(8))) short short8;
typedef __attribute__((ext_vector_type(4))) float float4v;
typedef __attribute__((ext_vector_type(2))) float f32x2;
typedef __attribute__((ext_vector_type(4))) float f32x4;

__device__ __forceinline__ f32x2 pk_fma(f32x2 a, f32x2 b, f32x2 c) {
#if __has_builtin(__builtin_elementwise_fma)
  return __builtin_elementwise_fma(a, b, c);
#else
  f32x2 r; r.x = fmaf(a.x, b.x, c.x); r.y = fmaf(a.y, b.y, c.y); return r;
#endif
}

__device__ __forceinline__ float wave_reduce_max(float v) {
#pragma unroll
  for (int off = 32; off > 0; off >>= 1) v = fmaxf(v, __shfl_xor(v, off, 64));
  return v;
}
__device__ __forceinline__ float wave_reduce_sum(float v) {
#pragma unroll
  for (int off = 32; off > 0; off >>= 1) v += __shfl_xor(v, off, 64);
  return v;
}
__device__ __forceinline__ unsigned pack_bf2(float a, float b) {
  __hip_bfloat162 h = __float22bfloat162_rn(make_float2(a, b));
  return *(unsigned*)&h;
}

// ---------------- x fp32 -> bf16 ----------------
__global__ __launch_bounds__(256) void conv_x(const float* __restrict__ x,
                                              unsigned short* __restrict__ xb) {
  int i = (blockIdx.x * 256 + threadIdx.x) * 8;
  float4 f0 = *(const float4*)&x[i];
  float4 f1 = *(const float4*)&x[i + 4];
  unsigned u[4] = {pack_bf2(f0.x, f0.y), pack_bf2(f0.z, f0.w),
                   pack_bf2(f1.x, f1.y), pack_bf2(f1.z, f1.w)};
  *(uint4*)&xb[i] = *(uint4*)u;
}

// ---------------- W transpose+convert: Wt[n][k] bf16 ----------------
__global__ __launch_bounds__(256) void conv_w(
    const float* __restrict__ Wq, const float* __restrict__ Wk,
    const float* __restrict__ Wv, const float* __restrict__ Wp,
    unsigned short* __restrict__ Wtq, unsigned short* __restrict__ Wtp) {
  __shared__ float Ts[64][65];
  const int k0 = blockIdx.x * 64;
  const int n0 = blockIdx.y * 64;
  const float* src; int ld, nc0; unsigned short* dst; int ndst;
  if (n0 < 512)       { src = Wq; ld = 512; nc0 = n0;        dst = Wtq; ndst = n0; }
  else if (n0 < 768)  { src = Wk; ld = 256; nc0 = n0 - 512;  dst = Wtq; ndst = n0; }
  else if (n0 < 1024) { src = Wv; ld = 256; nc0 = n0 - 768;  dst = Wtq; ndst = n0; }
  else                { src = Wp; ld = 512; nc0 = n0 - 1024; dst = Wtp; ndst = n0 - 1024; }
  const int t = threadIdx.x;
  const int r = t >> 4, c4 = (t & 15) << 2;
#pragma unroll
  for (int rr = 0; rr < 4; ++rr) {
    int row = (rr << 4) + r;
    float4 f = *(const float4*)&src[(k0 + row) * ld + nc0 + c4];
    Ts[row][c4] = f.x; Ts[row][c4 + 1] = f.y;
    Ts[row][c4 + 2] = f.z; Ts[row][c4 + 3] = f.w;
  }
  __syncthreads();
#pragma unroll
  for (int rr = 0; rr < 4; ++rr) {
    int nr = (rr << 4) + r;
    unsigned u0 = pack_bf2(Ts[c4][nr], Ts[c4 + 1][nr]);
    unsigned u1 = pack_bf2(Ts[c4 + 2][nr], Ts[c4 + 3][nr]);
    *(uint2*)&dst[(ndst + nr) * 512 + k0 + c4] = make_uint2(u0, u1);
  }
}

// ---------------- QKV MFMA GEMM ----------------
__global__ __launch_bounds__(256) void qkv_mfma(
    const unsigned short* __restrict__ xb, const unsigned short* __restrict__ Wt,
    float* __restrict__ q, float* __restrict__ k, float* __restrict__ v) {
  __shared__ unsigned short As[64][64];
  __shared__ unsigned short Bs[64][64];
  const int m0 = blockIdx.x * 64;
  const int n0 = blockIdx.y * 64;
  const int t = threadIdx.x;
  const int w = t >> 6, lane = t & 63;
  const int srow = t >> 2, sc = (t & 3) << 4;
  float4v acc[4] = {{0,0,0,0},{0,0,0,0},{0,0,0,0},{0,0,0,0}};
  for (int k0 = 0; k0 < 512; k0 += 64) {
    uint4 a0 = *(const uint4*)&xb[(m0 + srow) * 512 + k0 + sc];
    uint4 a1 = *(const uint4*)&xb[(m0 + srow) * 512 + k0 + sc + 8];
    uint4 b0 = *(const uint4*)&Wt[(n0 + srow) * 512 + k0 + sc];
    uint4 b1 = *(const uint4*)&Wt[(n0 + srow) * 512 + k0 + sc + 8];
    __syncthreads();
    *(uint4*)&As[srow][sc] = a0; *(uint4*)&As[srow][sc + 8] = a1;
    *(uint4*)&Bs[srow][sc] = b0; *(uint4*)&Bs[srow][sc + 8] = b1;
    __syncthreads();
    const int ml = (w << 4) + (lane & 15);
    const int kq = (lane >> 4) << 3;
    short8 aF0 = *(short8*)&As[ml][kq];
    short8 aF1 = *(short8*)&As[ml][kq + 32];
#pragma unroll
    for (int nt = 0; nt < 4; ++nt) {
      const int nl = (nt << 4) + (lane & 15);
      short8 bF0 = *(short8*)&Bs[nl][kq];
      short8 bF1 = *(short8*)&Bs[nl][kq + 32];
      acc[nt] = __builtin_amdgcn_mfma_f32_16x16x32_bf16(aF0, bF0, acc[nt], 0, 0, 0);
      acc[nt] = __builtin_amdgcn_mfma_f32_16x16x32_bf16(aF1, bF1, acc[nt], 0, 0, 0);
    }
  }
#pragma unroll
  for (int nt = 0; nt < 4; ++nt) {
    int col = n0 + (nt << 4) + (lane & 15);
#pragma unroll
    for (int r = 0; r < 4; ++r) {
      int row = m0 + (w << 4) + ((lane >> 4) << 2) + r;
      float val = acc[nt][r];
      if (col < 512)      q[row * 512 + col] = val;
      else if (col < 768) k[row * 256 + (col - 512)] = val;
      else                v[row * 256 + (col - 768)] = val;
    }
  }
}

// ---------------- Proj MFMA GEMM ----------------
__global__ __launch_bounds__(256) void proj_mfma(
    const unsigned short* __restrict__ yb, const unsigned short* __restrict__ Wt,
    float* __restrict__ out) {
  __shared__ unsigned short As[64][64];
  __shared__ unsigned short Bs[64][64];
  const int m0 = blockIdx.x * 64;
  const int n0 = blockIdx.y * 64;
  const int t = threadIdx.x;
  const int w = t >> 6, lane = t & 63;
  const int srow = t >> 2, sc = (t & 3) << 4;
  float4v acc[4] = {{0,0,0,0},{0,0,0,0},{0,0,0,0},{0,0,0,0}};
  for (int k0 = 0; k0 < 512; k0 += 64) {
    uint4 a0 = *(const uint4*)&yb[(m0 + srow) * 512 + k0 + sc];
    uint4 a1 = *(const uint4*)&yb[(m0 + srow) * 512 + k0 + sc + 8];
    uint4 b0 = *(const uint4*)&Wt[(n0 + srow) * 512 + k0 + sc];
    uint4 b1 = *(const uint4*)&Wt[(n0 + srow) * 512 + k0 + sc + 8];
    __syncthreads();
    *(uint4*)&As[srow][sc] = a0; *(uint4*)&As[srow][sc + 8] = a1;
    *(uint4*)&Bs[srow][sc] = b0; *(uint4*)&Bs[srow][sc + 8] = b1;
    __syncthreads();
    const int ml = (w << 4) + (lane & 15);
    const int kq = (lane >> 4) << 3;
    short8 aF0 = *(short8*)&As[ml][kq];
    short8 aF1 = *(short8*)&As[ml][kq + 32];
#pragma unroll
    for (int nt = 0; nt < 4; ++nt) {
      const int nl = (nt << 4) + (lane & 15);
      short8 bF0 = *(short8*)&Bs[nl][kq];
      short8 bF1 = *(short8*)&Bs[nl][kq + 32];
      acc[nt] = __builtin_amdgcn_mfma_f32_16x16x32_bf16(aF0, bF0, acc[nt], 0, 0, 0);
      acc[nt] = __builtin_amdgcn_mfma_f32_16x16x32_bf16(aF1, bF1, acc[nt], 0, 0, 0);
    }
  }
#pragma unroll
  for (int nt = 0; nt < 4; ++nt) {
    int col = n0 + (nt << 4) + (lane & 15);
#pragma unroll
    for (int r = 0; r < 4; ++r) {
      int row = m0 + (w << 4) + ((lane >> 4) << 2) + r;
      out[row * 512 + col] = acc[nt][r];
    }
  }
}

// ---------------- RMS-norm of q and k rows (64-wide) ----------------
__global__ __launch_bounds__(256) void norm_qk(float* __restrict__ q,
                                               float* __restrict__ k) {
  int w = blockIdx.x * 4 + (threadIdx.x >> 6);
  int lane = threadIdx.x & 63;
  float* row = (w < Bb * Tt * Hh) ? (q + w * 64) : (k + (w - Bb * Tt * Hh) * 64);
  float val = row[lane];
  float ss = wave_reduce_sum(val * val);
  row[lane] = val * 8.0f * rsqrtf(ss + 1e-6f);
}

// ---------------- Pw[h][delta+511][d] table ----------------
__global__ __launch_bounds__(256) void build_pw(const float* __restrict__ P,
                                                const float* __restrict__ sigma,
                                                float* __restrict__ Pw) {
  int idx = blockIdx.x * blockDim.x + threadIdx.x;
  if (idx >= Hh * 1023 * 64) return;
  int d = idx & 63;
  int rem = idx >> 6;
  int dd = rem % 1023;
  int h = rem / 1023;
  float s = fabsf(sigma[h]) + 1e-6f;
  float delta = (float)(dd - 511);
  float dt = 128.0f * tanhf(delta / s) + 128.0f;
  float lo = floorf(dt);
  int ilo = (int)lo;
  float frac = dt - lo;
  ilo = max(0, min(ilo, 256));
  int ihi = min(ilo + 1, 256);
  const float* Pb = P + h * 257 * 64;
  Pw[idx] = (1.0f - frac) * Pb[ilo * 64 + d] + frac * Pb[ihi * 64 + d];
}

// ---------------- Attention v5: 32-row i-blocks, packed fp32 math ----------------
// grid (T/32, B*H), block 256 = 4 waves; wave w owns i-rows i0+8w .. +7.
// LDS: Ks 17.4K + PwS[96] 25.5K + qS[32] 8.7K + pS[4][64][12] 12K = 63KB -> 2 blk/CU.
// Halves j-tile visits/barriers/staging vs 16-row blocks. Since jtmax <= i0,
// every staged j-tile is live for all rows (no per-row skip branch).
__global__ __launch_bounds__(256) void attn(
    const float* __restrict__ q, const float* __restrict__ k,
    const float* __restrict__ v, const float* __restrict__ Pw,
    unsigned short* __restrict__ yb) {
  __shared__ float Ks[64][68];
  __shared__ float PwS[96][68];
  __shared__ float qS[32][68];
  __shared__ float pS[4][64][12];  // 12-word stride: b128-aligned, bank-balanced

  const int t = threadIdx.x;
  const int w = t >> 6;
  const int lane = t & 63;
  const int bh = blockIdx.y;
  const int b = bh >> 3;
  const int h = bh & 7;
  const int hkv = h >> 1;
  const int i0 = blockIdx.x * 32;

  // stage q tile (32 rows)
  {
    int row = t >> 3, dc = (t & 7) << 3;
    const float* qp = &q[((b * Tt + i0 + row) * Hh + h) * Dd + dc];
    *(float4*)&qS[row][dc] = *(const float4*)&qp[0];
    *(float4*)&qS[row][dc + 4] = *(const float4*)&qp[4];
  }

  float m_run[8], l_run[8];
  f32x2 o2[4];
#pragma unroll
  for (int r = 0; r < 8; ++r) { m_run[r] = -1e30f; l_run[r] = 0.0f; }
#pragma unroll
  for (int pr = 0; pr < 4; ++pr) o2[pr] = (f32x2){0.0f, 0.0f};

  const int prow = (w << 3) + 63 - lane;
  const int i_base = i0 + (w << 3);

  for (int jt0 = 0; jt0 <= i0 + 31; jt0 += 64) {
    __syncthreads();
    {
      int jr = t >> 2, dc = (t & 3) << 4;
      const float* kp = &k[((b * Tt + jt0 + jr) * HKV + hkv) * Dd + dc];
#pragma unroll
      for (int c = 0; c < 4; ++c)
        *(float4*)&Ks[jr][dc + c * 4] = *(const float4*)&kp[c * 4];
      const int pb0 = h * 1023 + (i0 - jt0) + 448;  // Pw row for PwS row 0
      const float* pwp = &Pw[(pb0 + jr) * 64 + dc];
#pragma unroll
      for (int c = 0; c < 4; ++c)
        *(float4*)&PwS[jr][dc + c * 4] = *(const float4*)&pwp[c * 4];
      int pr2 = jr + 64;
      if (pr2 < 95) {
        const float* pwp2 = &Pw[(pb0 + pr2) * 64 + dc];
#pragma unroll
        for (int c = 0; c < 4; ++c)
          *(float4*)&PwS[pr2][dc + c * 4] = *(const float4*)&pwp2[c * 4];
      }
    }
    __syncthreads();

    // ---- score phase: lane = j, packed fp32 ----
    f32x2 s2[8];
#pragma unroll
    for (int r = 0; r < 8; ++r) s2[r] = (f32x2){0.0f, 0.0f};
#pragma unroll 4
    for (int dc = 0; dc < 64; dc += 4) {
      f32x4 kk = *(f32x4*)&Ks[lane][dc];
#pragma unroll
      for (int r = 0; r < 8; ++r) {
        f32x4 q4 = *(f32x4*)&qS[(w << 3) + r][dc];   // wave-uniform broadcast
        f32x4 p4 = *(f32x4*)&PwS[prow + r][dc];
        s2[r] = pk_fma(q4.xy * p4.xy, kk.xy, s2[r]);
        s2[r] = pk_fma(q4.zw * p4.zw, kk.zw, s2[r]);
      }
    }
    const int j = jt0 + lane;
    float pv[8];
#pragma unroll
    for (int r = 0; r < 8; ++r) {
      const int i_r = i_base + r;
      float sv = (j <= i_r) ? (s2[r].x + s2[r].y) * 0.125f : -1e30f;
      float mnew = fmaxf(m_run[r], wave_reduce_max(sv));
      float p = __expf(sv - mnew);
      float alpha = __expf(m_run[r] - mnew);
      l_run[r] = l_run[r] * alpha + wave_reduce_sum(p);
      m_run[r] = mnew;
      pv[r] = p;
      o2[r >> 1][r & 1] *= alpha;
    }
    *(float4*)&pS[w][lane][0] = make_float4(pv[0], pv[1], pv[2], pv[3]);
    *(float4*)&pS[w][lane][4] = make_float4(pv[4], pv[5], pv[6], pv[7]);

    // ---- PV phase: lane = d; V coalesced from global (same-wave pS ordering) ----
    const float* vp = &v[((b * Tt + jt0) * HKV + hkv) * Dd + lane];
#pragma unroll 8
    for (int jj = 0; jj < 64; ++jj) {
      f32x4 pa = *(f32x4*)&pS[w][jj][0];
      f32x4 pb = *(f32x4*)&pS[w][jj][4];
      float vv = vp[jj * (HKV * Dd)];
      f32x2 vv2 = {vv, vv};
      o2[0] = pk_fma(pa.xy, vv2, o2[0]);
      o2[1] = pk_fma(pa.zw, vv2, o2[1]);
      o2[2] = pk_fma(pb.xy, vv2, o2[2]);
      o2[3] = pk_fma(pb.zw, vv2, o2[3]);
    }
  }
#pragma unroll
  for (int r = 0; r < 8; ++r) {
    const int i_r = i_base + r;
    float val = o2[r >> 1][r & 1] / l_run[r];
    __hip_bfloat16 hv = __float2bfloat16(val);
    yb[((b * Tt + i_r) * Hh + h) * Dd + lane] = *(unsigned short*)&hv;
  }
}

extern "C" void kernel_launch(void* const* d_in, const int* in_sizes, int n_in,
                              void* d_out, int out_size, void* d_ws, size_t ws_size,
                              hipStream_t stream) {
  const float* x     = (const float*)d_in[0];
  const float* Wq    = (const float*)d_in[1];
  const float* Wk    = (const float*)d_in[2];
  const float* Wv    = (const float*)d_in[3];
  const float* Wproj = (const float*)d_in[4];
  const float* P     = (const float*)d_in[5];
  const float* sigma = (const float*)d_in[6];
  float* out = (float*)d_out;

  float* ws = (float*)d_ws;
  float* q  = ws;                              // 2,097,152 f
  float* k  = q + 2097152;                     // 1,048,576 f
  float* v  = k + 1048576;                     // 1,048,576 f
  float* Pw = v + 1048576;                     // 523,776 f (pad to 524,288)
  unsigned short* xb  = (unsigned short*)(ws + 4718592);  // 2M bf16
  unsigned short* yb  = xb;                               // aliased: xb dead after qkv_mfma
  unsigned short* Wtq = (unsigned short*)(ws + 5767168);  // 512K bf16
  unsigned short* Wtp = (unsigned short*)(ws + 6029312);  // 256K bf16

  conv_x<<<dim3(1024), 256, 0, stream>>>(x, xb);
  conv_w<<<dim3(8, 24), 256, 0, stream>>>(Wq, Wk, Wv, Wproj, Wtq, Wtp);
  qkv_mfma<<<dim3(64, 16), 256, 0, stream>>>(xb, Wtq, q, k, v);
  norm_qk<<<dim3(12288), 256, 0, stream>>>(q, k);
  build_pw<<<dim3(2046), 256, 0, stream>>>(P, sigma, Pw);
  attn<<<dim3(16, 64), 256, 0, stream>>>(q, k, v, Pw, yb);
  proj_mfma<<<dim3(64, 8), 256, 0, stream>>>(yb, Wtp, out);
}

// Round 7
// 227.309 us; speedup vs baseline: 2.8598x; 1.3113x over previous
//
#include <hip/hip_runtime.h>
#include <hip/hip_bf16.h>
#include <math.h>

#define Bb 8
#define Tt 512
#define Cc 512
#define Hh 8
#define HKV 4
#define Dd 64

typedef __attribute__((ext_vector_type(8))) short short8;
typedef __attribute__((ext_vector_type(4))) float float4v;
typedef __attribute__((ext_vector_type(2))) __fp16 h2;  // matches cvt_pkrtz return type

__device__ __forceinline__ h2 u2h(unsigned u) {
  union { unsigned u; h2 h; } x; x.u = u; return x.h;
}
__device__ __forceinline__ unsigned h2u(h2 h) {
  union { h2 h; unsigned u; } x; x.h = h; return x.u;
}
__device__ __forceinline__ float fdot2(h2 a, h2 b, float c) {
#if __has_builtin(__builtin_amdgcn_fdot2)
  return __builtin_amdgcn_fdot2(a, b, c, false);
#else
  return fmaf((float)a.x, (float)b.x, fmaf((float)a.y, (float)b.y, c));
#endif
}

__device__ __forceinline__ float wave_reduce_max(float v) {
#pragma unroll
  for (int off = 32; off > 0; off >>= 1) v = fmaxf(v, __shfl_xor(v, off, 64));
  return v;
}
__device__ __forceinline__ float wave_reduce_sum(float v) {
#pragma unroll
  for (int off = 32; off > 0; off >>= 1) v += __shfl_xor(v, off, 64);
  return v;
}
__device__ __forceinline__ unsigned pack_bf2(float a, float b) {
  __hip_bfloat162 h = __float22bfloat162_rn(make_float2(a, b));
  return *(unsigned*)&h;
}

// ---------------- x fp32 -> bf16 ----------------
__global__ __launch_bounds__(256) void conv_x(const float* __restrict__ x,
                                              unsigned short* __restrict__ xb) {
  int i = (blockIdx.x * 256 + threadIdx.x) * 8;
  float4 f0 = *(const float4*)&x[i];
  float4 f1 = *(const float4*)&x[i + 4];
  unsigned u[4] = {pack_bf2(f0.x, f0.y), pack_bf2(f0.z, f0.w),
                   pack_bf2(f1.x, f1.y), pack_bf2(f1.z, f1.w)};
  *(uint4*)&xb[i] = *(uint4*)u;
}

// ---------------- W transpose+convert: Wt[n][k] bf16 ----------------
__global__ __launch_bounds__(256) void conv_w(
    const float* __restrict__ Wq, const float* __restrict__ Wk,
    const float* __restrict__ Wv, const float* __restrict__ Wp,
    unsigned short* __restrict__ Wtq, unsigned short* __restrict__ Wtp) {
  __shared__ float Ts[64][65];
  const int k0 = blockIdx.x * 64;
  const int n0 = blockIdx.y * 64;
  const float* src; int ld, nc0; unsigned short* dst; int ndst;
  if (n0 < 512)       { src = Wq; ld = 512; nc0 = n0;        dst = Wtq; ndst = n0; }
  else if (n0 < 768)  { src = Wk; ld = 256; nc0 = n0 - 512;  dst = Wtq; ndst = n0; }
  else if (n0 < 1024) { src = Wv; ld = 256; nc0 = n0 - 768;  dst = Wtq; ndst = n0; }
  else                { src = Wp; ld = 512; nc0 = n0 - 1024; dst = Wtp; ndst = n0 - 1024; }
  const int t = threadIdx.x;
  const int r = t >> 4, c4 = (t & 15) << 2;
#pragma unroll
  for (int rr = 0; rr < 4; ++rr) {
    int row = (rr << 4) + r;
    float4 f = *(const float4*)&src[(k0 + row) * ld + nc0 + c4];
    Ts[row][c4] = f.x; Ts[row][c4 + 1] = f.y;
    Ts[row][c4 + 2] = f.z; Ts[row][c4 + 3] = f.w;
  }
  __syncthreads();
#pragma unroll
  for (int rr = 0; rr < 4; ++rr) {
    int nr = (rr << 4) + r;
    unsigned u0 = pack_bf2(Ts[c4][nr], Ts[c4 + 1][nr]);
    unsigned u1 = pack_bf2(Ts[c4 + 2][nr], Ts[c4 + 3][nr]);
    *(uint2*)&dst[(ndst + nr) * 512 + k0 + c4] = make_uint2(u0, u1);
  }
}

// ---------------- QKV MFMA GEMM ----------------
__global__ __launch_bounds__(256) void qkv_mfma(
    const unsigned short* __restrict__ xb, const unsigned short* __restrict__ Wt,
    float* __restrict__ q, float* __restrict__ k, float* __restrict__ v) {
  __shared__ unsigned short As[64][64];
  __shared__ unsigned short Bs[64][64];
  const int m0 = blockIdx.x * 64;
  const int n0 = blockIdx.y * 64;
  const int t = threadIdx.x;
  const int w = t >> 6, lane = t & 63;
  const int srow = t >> 2, sc = (t & 3) << 4;
  float4v acc[4] = {{0,0,0,0},{0,0,0,0},{0,0,0,0},{0,0,0,0}};
  for (int k0 = 0; k0 < 512; k0 += 64) {
    uint4 a0 = *(const uint4*)&xb[(m0 + srow) * 512 + k0 + sc];
    uint4 a1 = *(const uint4*)&xb[(m0 + srow) * 512 + k0 + sc + 8];
    uint4 b0 = *(const uint4*)&Wt[(n0 + srow) * 512 + k0 + sc];
    uint4 b1 = *(const uint4*)&Wt[(n0 + srow) * 512 + k0 + sc + 8];
    __syncthreads();
    *(uint4*)&As[srow][sc] = a0; *(uint4*)&As[srow][sc + 8] = a1;
    *(uint4*)&Bs[srow][sc] = b0; *(uint4*)&Bs[srow][sc + 8] = b1;
    __syncthreads();
    const int ml = (w << 4) + (lane & 15);
    const int kq = (lane >> 4) << 3;
    short8 aF0 = *(short8*)&As[ml][kq];
    short8 aF1 = *(short8*)&As[ml][kq + 32];
#pragma unroll
    for (int nt = 0; nt < 4; ++nt) {
      const int nl = (nt << 4) + (lane & 15);
      short8 bF0 = *(short8*)&Bs[nl][kq];
      short8 bF1 = *(short8*)&Bs[nl][kq + 32];
      acc[nt] = __builtin_amdgcn_mfma_f32_16x16x32_bf16(aF0, bF0, acc[nt], 0, 0, 0);
      acc[nt] = __builtin_amdgcn_mfma_f32_16x16x32_bf16(aF1, bF1, acc[nt], 0, 0, 0);
    }
  }
#pragma unroll
  for (int nt = 0; nt < 4; ++nt) {
    int col = n0 + (nt << 4) + (lane & 15);
#pragma unroll
    for (int r = 0; r < 4; ++r) {
      int row = m0 + (w << 4) + ((lane >> 4) << 2) + r;
      float val = acc[nt][r];
      if (col < 512)      q[row * 512 + col] = val;
      else if (col < 768) k[row * 256 + (col - 512)] = val;
      else                v[row * 256 + (col - 768)] = val;
    }
  }
}

// ---------------- Proj MFMA GEMM ----------------
__global__ __launch_bounds__(256) void proj_mfma(
    const unsigned short* __restrict__ yb, const unsigned short* __restrict__ Wt,
    float* __restrict__ out) {
  __shared__ unsigned short As[64][64];
  __shared__ unsigned short Bs[64][64];
  const int m0 = blockIdx.x * 64;
  const int n0 = blockIdx.y * 64;
  const int t = threadIdx.x;
  const int w = t >> 6, lane = t & 63;
  const int srow = t >> 2, sc = (t & 3) << 4;
  float4v acc[4] = {{0,0,0,0},{0,0,0,0},{0,0,0,0},{0,0,0,0}};
  for (int k0 = 0; k0 < 512; k0 += 64) {
    uint4 a0 = *(const uint4*)&yb[(m0 + srow) * 512 + k0 + sc];
    uint4 a1 = *(const uint4*)&yb[(m0 + srow) * 512 + k0 + sc + 8];
    uint4 b0 = *(const uint4*)&Wt[(n0 + srow) * 512 + k0 + sc];
    uint4 b1 = *(const uint4*)&Wt[(n0 + srow) * 512 + k0 + sc + 8];
    __syncthreads();
    *(uint4*)&As[srow][sc] = a0; *(uint4*)&As[srow][sc + 8] = a1;
    *(uint4*)&Bs[srow][sc] = b0; *(uint4*)&Bs[srow][sc + 8] = b1;
    __syncthreads();
    const int ml = (w << 4) + (lane & 15);
    const int kq = (lane >> 4) << 3;
    short8 aF0 = *(short8*)&As[ml][kq];
    short8 aF1 = *(short8*)&As[ml][kq + 32];
#pragma unroll
    for (int nt = 0; nt < 4; ++nt) {
      const int nl = (nt << 4) + (lane & 15);
      short8 bF0 = *(short8*)&Bs[nl][kq];
      short8 bF1 = *(short8*)&Bs[nl][kq + 32];
      acc[nt] = __builtin_amdgcn_mfma_f32_16x16x32_bf16(aF0, bF0, acc[nt], 0, 0, 0);
      acc[nt] = __builtin_amdgcn_mfma_f32_16x16x32_bf16(aF1, bF1, acc[nt], 0, 0, 0);
    }
  }
#pragma unroll
  for (int nt = 0; nt < 4; ++nt) {
    int col = n0 + (nt << 4) + (lane & 15);
#pragma unroll
    for (int r = 0; r < 4; ++r) {
      int row = m0 + (w << 4) + ((lane >> 4) << 2) + r;
      out[row * 512 + col] = acc[nt][r];
    }
  }
}

// ---------------- RMS-norm of q and k rows (64-wide) ----------------
__global__ __launch_bounds__(256) void norm_qk(float* __restrict__ q,
                                               float* __restrict__ k) {
  int w = blockIdx.x * 4 + (threadIdx.x >> 6);
  int lane = threadIdx.x & 63;
  float* row = (w < Bb * Tt * Hh) ? (q + w * 64) : (k + (w - Bb * Tt * Hh) * 64);
  float val = row[lane];
  float ss = wave_reduce_sum(val * val);
  row[lane] = val * 8.0f * rsqrtf(ss + 1e-6f);
}

// ---------------- Pw[h][delta+511][d] table ----------------
__global__ __launch_bounds__(256) void build_pw(const float* __restrict__ P,
                                                const float* __restrict__ sigma,
                                                float* __restrict__ Pw) {
  int idx = blockIdx.x * blockDim.x + threadIdx.x;
  if (idx >= Hh * 1023 * 64) return;
  int d = idx & 63;
  int rem = idx >> 6;
  int dd = rem % 1023;
  int h = rem / 1023;
  float s = fabsf(sigma[h]) + 1e-6f;
  float delta = (float)(dd - 511);
  float dt = 128.0f * tanhf(delta / s) + 128.0f;
  float lo = floorf(dt);
  int ilo = (int)lo;
  float frac = dt - lo;
  ilo = max(0, min(ilo, 256));
  int ihi = min(ilo + 1, 256);
  const float* Pb = P + h * 257 * 64;
  Pw[idx] = (1.0f - frac) * Pb[ilo * 64 + d] + frac * Pb[ihi * 64 + d];
}

// ---------------- Attention v6: fp16 LDS + pk_mul/fdot2 consumers ----------------
// grid (T/32, B*H), block 256 = 4 waves; wave w owns i-rows i0+8w .. +7.
// LDS fp16: Ks 9K + PwS[96] 13.5K + qS 4.5K + pS 4K = 31KB -> 4 blocks/CU.
// fp16 feeds v_pk_mul_f16 / v_dot2_f32_f16 directly (no unpack, fp32 accum) --
// avoids round-3's unpack-VALU/VGPR blowup while halving LDS b128 traffic.
__global__ __launch_bounds__(256) void attn(
    const float* __restrict__ q, const float* __restrict__ k,
    const float* __restrict__ v, const float* __restrict__ Pw,
    unsigned short* __restrict__ yb) {
  __shared__ __fp16 Ks[64][72];
  __shared__ __fp16 PwS[96][72];
  __shared__ __fp16 qS[32][72];
  __shared__ __fp16 pS[4][32][16];  // [wave][j-pair][2r..2r+1]=(p[r][2j2],p[r][2j2+1])

  const int t = threadIdx.x;
  const int w = t >> 6;
  const int lane = t & 63;
  const int bh = blockIdx.y;
  const int b = bh >> 3;
  const int h = bh & 7;
  const int hkv = h >> 1;
  const int i0 = blockIdx.x * 32;

  // stage q tile (32 rows x 64) as fp16: thread t -> row t>>3, 8 elems at (t&7)*8
  {
    int row = t >> 3, dc = (t & 7) << 3;
    const float* qp = &q[((b * Tt + i0 + row) * Hh + h) * Dd + dc];
    float4 f0 = *(const float4*)&qp[0];
    float4 f1 = *(const float4*)&qp[4];
    unsigned u[4] = {h2u(__builtin_amdgcn_cvt_pkrtz(f0.x, f0.y)),
                     h2u(__builtin_amdgcn_cvt_pkrtz(f0.z, f0.w)),
                     h2u(__builtin_amdgcn_cvt_pkrtz(f1.x, f1.y)),
                     h2u(__builtin_amdgcn_cvt_pkrtz(f1.z, f1.w))};
    *(uint4*)&qS[row][dc] = *(uint4*)u;
  }

  float m_run[8], l_run[8], o_run[8];
#pragma unroll
  for (int r = 0; r < 8; ++r) { m_run[r] = -1e30f; l_run[r] = 0.0f; o_run[r] = 0.0f; }

  const int prow = (w << 3) + 63 - lane;
  const int i_base = i0 + (w << 3);

  for (int jt0 = 0; jt0 <= i0 + 31; jt0 += 64) {
    __syncthreads();
    {
      // K rows 0..63: thread t -> row t>>2, 16 elems at (t&3)*16
      int jr = t >> 2, dc = (t & 3) << 4;
      const float* kp = &k[((b * Tt + jt0 + jr) * HKV + hkv) * Dd + dc];
      unsigned u[8];
#pragma unroll
      for (int c = 0; c < 4; ++c) {
        float4 f = *(const float4*)&kp[c * 4];
        u[c * 2]     = h2u(__builtin_amdgcn_cvt_pkrtz(f.x, f.y));
        u[c * 2 + 1] = h2u(__builtin_amdgcn_cvt_pkrtz(f.z, f.w));
      }
      *(uint4*)&Ks[jr][dc]     = *(uint4*)&u[0];
      *(uint4*)&Ks[jr][dc + 8] = *(uint4*)&u[4];

      const int pb0 = h * 1023 + (i0 - jt0) + 448;  // Pw row for PwS row 0
      const float* pwp = &Pw[(pb0 + jr) * 64 + dc];
#pragma unroll
      for (int c = 0; c < 4; ++c) {
        float4 f = *(const float4*)&pwp[c * 4];
        u[c * 2]     = h2u(__builtin_amdgcn_cvt_pkrtz(f.x, f.y));
        u[c * 2 + 1] = h2u(__builtin_amdgcn_cvt_pkrtz(f.z, f.w));
      }
      *(uint4*)&PwS[jr][dc]     = *(uint4*)&u[0];
      *(uint4*)&PwS[jr][dc + 8] = *(uint4*)&u[4];

      // PwS rows 64..94: thread t -> row 64+(t>>3), 8 elems at (t&7)*8
      int pr2 = 64 + (t >> 3), dc2 = (t & 7) << 3;
      if (pr2 < 95) {
        const float* pwp2 = &Pw[(pb0 + pr2) * 64 + dc2];
        float4 f0 = *(const float4*)&pwp2[0];
        float4 f1 = *(const float4*)&pwp2[4];
        unsigned u2[4] = {h2u(__builtin_amdgcn_cvt_pkrtz(f0.x, f0.y)),
                          h2u(__builtin_amdgcn_cvt_pkrtz(f0.z, f0.w)),
                          h2u(__builtin_amdgcn_cvt_pkrtz(f1.x, f1.y)),
                          h2u(__builtin_amdgcn_cvt_pkrtz(f1.z, f1.w))};
        *(uint4*)&PwS[pr2][dc2] = *(uint4*)u2;
      }
    }
    __syncthreads();

    // ---- score phase: lane = j; fp16 pk_mul + fdot2, fp32 accumulation ----
    float s[8];
#pragma unroll
    for (int r = 0; r < 8; ++r) s[r] = 0.0f;
#pragma unroll
    for (int ch = 0; ch < 8; ++ch) {
      const int dc = ch << 3;
      uint4 ku = *(uint4*)&Ks[lane][dc];
      h2 k0 = u2h(ku.x), k1 = u2h(ku.y), k2 = u2h(ku.z), k3 = u2h(ku.w);
#pragma unroll
      for (int r = 0; r < 8; ++r) {
        uint4 qu = *(uint4*)&qS[(w << 3) + r][dc];     // wave-uniform broadcast
        uint4 pu = *(uint4*)&PwS[prow + r][dc];
        s[r] = fdot2(u2h(qu.x) * u2h(pu.x), k0, s[r]);
        s[r] = fdot2(u2h(qu.y) * u2h(pu.y), k1, s[r]);
        s[r] = fdot2(u2h(qu.z) * u2h(pu.z), k2, s[r]);
        s[r] = fdot2(u2h(qu.w) * u2h(pu.w), k3, s[r]);
      }
    }
    const int j = jt0 + lane;
    float pv[8];
#pragma unroll
    for (int r = 0; r < 8; ++r) {
      const int i_r = i_base + r;
      float sv = (j <= i_r) ? s[r] * 0.125f : -1e30f;
      float mnew = fmaxf(m_run[r], wave_reduce_max(sv));
      float p = __expf(sv - mnew);
      float alpha = __expf(m_run[r] - mnew);
      l_run[r] = l_run[r] * alpha + wave_reduce_sum(p);
      m_run[r] = mnew;
      pv[r] = p;
      o_run[r] *= alpha;
    }
    // transpose p to fp16 j-pairs: lanes (2m,2m+1) -> pS[w][m][2r..2r+1]
    {
      unsigned u[8];
#pragma unroll
      for (int r = 0; r < 8; ++r) {
        float other = __shfl_xor(pv[r], 1, 64);
        u[r] = h2u(__builtin_amdgcn_cvt_pkrtz(pv[r], other));
      }
      if (!(lane & 1)) {
        *(uint4*)&pS[w][lane >> 1][0] = *(uint4*)&u[0];
        *(uint4*)&pS[w][lane >> 1][8] = *(uint4*)&u[4];
      }
    }

    // ---- PV phase: lane = d; fdot2 over j-pairs, V from global (coalesced) ----
    const float* vp = &v[((b * Tt + jt0) * HKV + hkv) * Dd + lane];
#pragma unroll 4
    for (int j2 = 0; j2 < 32; ++j2) {
      uint4 p0 = *(uint4*)&pS[w][j2][0];   // broadcast
      uint4 p1 = *(uint4*)&pS[w][j2][8];
      float va = vp[(2 * j2) * (HKV * Dd)];
      float vb = vp[(2 * j2 + 1) * (HKV * Dd)];
      h2 vv = __builtin_amdgcn_cvt_pkrtz(va, vb);
      o_run[0] = fdot2(u2h(p0.x), vv, o_run[0]);
      o_run[1] = fdot2(u2h(p0.y), vv, o_run[1]);
      o_run[2] = fdot2(u2h(p0.z), vv, o_run[2]);
      o_run[3] = fdot2(u2h(p0.w), vv, o_run[3]);
      o_run[4] = fdot2(u2h(p1.x), vv, o_run[4]);
      o_run[5] = fdot2(u2h(p1.y), vv, o_run[5]);
      o_run[6] = fdot2(u2h(p1.z), vv, o_run[6]);
      o_run[7] = fdot2(u2h(p1.w), vv, o_run[7]);
    }
  }
#pragma unroll
  for (int r = 0; r < 8; ++r) {
    const int i_r = i_base + r;
    __hip_bfloat16 hv = __float2bfloat16(o_run[r] / l_run[r]);
    yb[((b * Tt + i_r) * Hh + h) * Dd + lane] = *(unsigned short*)&hv;
  }
}

extern "C" void kernel_launch(void* const* d_in, const int* in_sizes, int n_in,
                              void* d_out, int out_size, void* d_ws, size_t ws_size,
                              hipStream_t stream) {
  const float* x     = (const float*)d_in[0];
  const float* Wq    = (const float*)d_in[1];
  const float* Wk    = (const float*)d_in[2];
  const float* Wv    = (const float*)d_in[3];
  const float* Wproj = (const float*)d_in[4];
  const float* P     = (const float*)d_in[5];
  const float* sigma = (const float*)d_in[6];
  float* out = (float*)d_out;

  float* ws = (float*)d_ws;
  float* q  = ws;                              // 2,097,152 f
  float* k  = q + 2097152;                     // 1,048,576 f
  float* v  = k + 1048576;                     // 1,048,576 f
  float* Pw = v + 1048576;                     // 523,776 f (pad to 524,288)
  unsigned short* xb  = (unsigned short*)(ws + 4718592);  // 2M bf16
  unsigned short* yb  = xb;                               // aliased: xb dead after qkv_mfma
  unsigned short* Wtq = (unsigned short*)(ws + 5767168);  // 512K bf16
  unsigned short* Wtp = (unsigned short*)(ws + 6029312);  // 256K bf16

  conv_x<<<dim3(1024), 256, 0, stream>>>(x, xb);
  conv_w<<<dim3(8, 24), 256, 0, stream>>>(Wq, Wk, Wv, Wproj, Wtq, Wtp);
  qkv_mfma<<<dim3(64, 16), 256, 0, stream>>>(xb, Wtq, q, k, v);
  norm_qk<<<dim3(12288), 256, 0, stream>>>(q, k);
  build_pw<<<dim3(2046), 256, 0, stream>>>(P, sigma, Pw);
  attn<<<dim3(16, 64), 256, 0, stream>>>(q, k, v, Pw, yb);
  proj_mfma<<<dim3(64, 8), 256, 0, stream>>>(yb, Wtp, out);
}

// Round 8
// 167.294 us; speedup vs baseline: 3.8858x; 1.3587x over previous
//
#include <hip/hip_runtime.h>
#include <hip/hip_bf16.h>
#include <math.h>

#define Bb 8
#define Tt 512
#define Cc 512
#define Hh 8
#define HKV 4
#define Dd 64

typedef __attribute__((ext_vector_type(8))) short short8;
typedef __attribute__((ext_vector_type(4))) float float4v;
typedef __attribute__((ext_vector_type(2))) __fp16 h2;  // matches cvt_pkrtz return type

__device__ __forceinline__ h2 u2h(unsigned u) {
  union { unsigned u; h2 h; } x; x.u = u; return x.h;
}
__device__ __forceinline__ unsigned h2u(h2 h) {
  union { h2 h; unsigned u; } x; x.h = h; return x.u;
}
__device__ __forceinline__ float fdot2(h2 a, h2 b, float c) {
#if __has_builtin(__builtin_amdgcn_fdot2)
  return __builtin_amdgcn_fdot2(a, b, c, false);
#else
  return fmaf((float)a.x, (float)b.x, fmaf((float)a.y, (float)b.y, c));
#endif
}

__device__ __forceinline__ float wave_reduce_max(float v) {
#pragma unroll
  for (int off = 32; off > 0; off >>= 1) v = fmaxf(v, __shfl_xor(v, off, 64));
  return v;
}
__device__ __forceinline__ float wave_reduce_sum(float v) {
#pragma unroll
  for (int off = 32; off > 0; off >>= 1) v += __shfl_xor(v, off, 64);
  return v;
}
__device__ __forceinline__ unsigned pack_bf2(float a, float b) {
  __hip_bfloat162 h = __float22bfloat162_rn(make_float2(a, b));
  return *(unsigned*)&h;
}

// ---------------- x fp32 -> bf16 ----------------
__global__ __launch_bounds__(256) void conv_x(const float* __restrict__ x,
                                              unsigned short* __restrict__ xb) {
  int i = (blockIdx.x * 256 + threadIdx.x) * 8;
  float4 f0 = *(const float4*)&x[i];
  float4 f1 = *(const float4*)&x[i + 4];
  unsigned u[4] = {pack_bf2(f0.x, f0.y), pack_bf2(f0.z, f0.w),
                   pack_bf2(f1.x, f1.y), pack_bf2(f1.z, f1.w)};
  *(uint4*)&xb[i] = *(uint4*)u;
}

// ---------------- W transpose+convert: Wt[n][k] bf16 ----------------
__global__ __launch_bounds__(256) void conv_w(
    const float* __restrict__ Wq, const float* __restrict__ Wk,
    const float* __restrict__ Wv, const float* __restrict__ Wp,
    unsigned short* __restrict__ Wtq, unsigned short* __restrict__ Wtp) {
  __shared__ float Ts[64][65];
  const int k0 = blockIdx.x * 64;
  const int n0 = blockIdx.y * 64;
  const float* src; int ld, nc0; unsigned short* dst; int ndst;
  if (n0 < 512)       { src = Wq; ld = 512; nc0 = n0;        dst = Wtq; ndst = n0; }
  else if (n0 < 768)  { src = Wk; ld = 256; nc0 = n0 - 512;  dst = Wtq; ndst = n0; }
  else if (n0 < 1024) { src = Wv; ld = 256; nc0 = n0 - 768;  dst = Wtq; ndst = n0; }
  else                { src = Wp; ld = 512; nc0 = n0 - 1024; dst = Wtp; ndst = n0 - 1024; }
  const int t = threadIdx.x;
  const int r = t >> 4, c4 = (t & 15) << 2;
#pragma unroll
  for (int rr = 0; rr < 4; ++rr) {
    int row = (rr << 4) + r;
    float4 f = *(const float4*)&src[(k0 + row) * ld + nc0 + c4];
    Ts[row][c4] = f.x; Ts[row][c4 + 1] = f.y;
    Ts[row][c4 + 2] = f.z; Ts[row][c4 + 3] = f.w;
  }
  __syncthreads();
#pragma unroll
  for (int rr = 0; rr < 4; ++rr) {
    int nr = (rr << 4) + r;
    unsigned u0 = pack_bf2(Ts[c4][nr], Ts[c4 + 1][nr]);
    unsigned u1 = pack_bf2(Ts[c4 + 2][nr], Ts[c4 + 3][nr]);
    *(uint2*)&dst[(ndst + nr) * 512 + k0 + c4] = make_uint2(u0, u1);
  }
}

// ---------------- QKV MFMA GEMM + fused RMS-norm + fp16 emit ----------------
// q (n0<512): norm + fp16 -> qh[t][h][d]
// k (512<=n0<768): norm + fp16 -> kh[t][hkv][d]
// v (n0>=768): paired fp16 (rows 2j,2j+1) -> vhu[t/2][hkv][d]
__global__ __launch_bounds__(256) void qkv_mfma(
    const unsigned short* __restrict__ xb, const unsigned short* __restrict__ Wt,
    unsigned short* __restrict__ qh, unsigned short* __restrict__ kh,
    unsigned* __restrict__ vhu) {
  __shared__ unsigned short As[64][64];
  __shared__ unsigned short Bs[64][64];
  const int m0 = blockIdx.x * 64;
  const int n0 = blockIdx.y * 64;
  const int t = threadIdx.x;
  const int w = t >> 6, lane = t & 63;
  const int srow = t >> 2, sc = (t & 3) << 4;
  float4v acc[4] = {{0,0,0,0},{0,0,0,0},{0,0,0,0},{0,0,0,0}};
  for (int k0 = 0; k0 < 512; k0 += 64) {
    uint4 a0 = *(const uint4*)&xb[(m0 + srow) * 512 + k0 + sc];
    uint4 a1 = *(const uint4*)&xb[(m0 + srow) * 512 + k0 + sc + 8];
    uint4 b0 = *(const uint4*)&Wt[(n0 + srow) * 512 + k0 + sc];
    uint4 b1 = *(const uint4*)&Wt[(n0 + srow) * 512 + k0 + sc + 8];
    __syncthreads();
    *(uint4*)&As[srow][sc] = a0; *(uint4*)&As[srow][sc + 8] = a1;
    *(uint4*)&Bs[srow][sc] = b0; *(uint4*)&Bs[srow][sc + 8] = b1;
    __syncthreads();
    const int ml = (w << 4) + (lane & 15);
    const int kq = (lane >> 4) << 3;
    short8 aF0 = *(short8*)&As[ml][kq];
    short8 aF1 = *(short8*)&As[ml][kq + 32];
#pragma unroll
    for (int nt = 0; nt < 4; ++nt) {
      const int nl = (nt << 4) + (lane & 15);
      short8 bF0 = *(short8*)&Bs[nl][kq];
      short8 bF1 = *(short8*)&Bs[nl][kq + 32];
      acc[nt] = __builtin_amdgcn_mfma_f32_16x16x32_bf16(aF0, bF0, acc[nt], 0, 0, 0);
      acc[nt] = __builtin_amdgcn_mfma_f32_16x16x32_bf16(aF1, bF1, acc[nt], 0, 0, 0);
    }
  }
  const int lane15 = lane & 15;
  const int rowbase = m0 + (w << 4) + ((lane >> 4) << 2);
  if (n0 < 768) {
    // q or k head: fused RMS-norm over the 64-wide head (= this n-tile)
#pragma unroll
    for (int r = 0; r < 4; ++r) {
      float ss = 0.0f;
#pragma unroll
      for (int nt = 0; nt < 4; ++nt) ss = fmaf(acc[nt][r], acc[nt][r], ss);
#pragma unroll
      for (int off = 1; off < 16; off <<= 1) ss += __shfl_xor(ss, off, 64);
      float sc2 = 8.0f * rsqrtf(ss + 1e-6f);
      const int row = rowbase + r;
      if (n0 < 512) {
        const int h = n0 >> 6;
#pragma unroll
        for (int nt = 0; nt < 4; ++nt) {
          __fp16 hv = (__fp16)(acc[nt][r] * sc2);
          qh[(row * Hh + h) * Dd + (nt << 4) + lane15] = *(unsigned short*)&hv;
        }
      } else {
        const int hkv = (n0 - 512) >> 6;
#pragma unroll
        for (int nt = 0; nt < 4; ++nt) {
          __fp16 hv = (__fp16)(acc[nt][r] * sc2);
          kh[(row * HKV + hkv) * Dd + (nt << 4) + lane15] = *(unsigned short*)&hv;
        }
      }
    }
  } else {
    // v: pack row-pairs (2j, 2j+1) as h2 -> vhu[rowpair][hkv][d]
    const int hkv = (n0 - 768) >> 6;
#pragma unroll
    for (int r = 0; r < 4; r += 2) {
      const int rp = (rowbase + r) >> 1;
#pragma unroll
      for (int nt = 0; nt < 4; ++nt) {
        unsigned u = h2u(__builtin_amdgcn_cvt_pkrtz(acc[nt][r], acc[nt][r + 1]));
        vhu[(rp * HKV + hkv) * Dd + (nt << 4) + lane15] = u;
      }
    }
  }
}

// ---------------- Proj MFMA GEMM ----------------
__global__ __launch_bounds__(256) void proj_mfma(
    const unsigned short* __restrict__ yb, const unsigned short* __restrict__ Wt,
    float* __restrict__ out) {
  __shared__ unsigned short As[64][64];
  __shared__ unsigned short Bs[64][64];
  const int m0 = blockIdx.x * 64;
  const int n0 = blockIdx.y * 64;
  const int t = threadIdx.x;
  const int w = t >> 6, lane = t & 63;
  const int srow = t >> 2, sc = (t & 3) << 4;
  float4v acc[4] = {{0,0,0,0},{0,0,0,0},{0,0,0,0},{0,0,0,0}};
  for (int k0 = 0; k0 < 512; k0 += 64) {
    uint4 a0 = *(const uint4*)&yb[(m0 + srow) * 512 + k0 + sc];
    uint4 a1 = *(const uint4*)&yb[(m0 + srow) * 512 + k0 + sc + 8];
    uint4 b0 = *(const uint4*)&Wt[(n0 + srow) * 512 + k0 + sc];
    uint4 b1 = *(const uint4*)&Wt[(n0 + srow) * 512 + k0 + sc + 8];
    __syncthreads();
    *(uint4*)&As[srow][sc] = a0; *(uint4*)&As[srow][sc + 8] = a1;
    *(uint4*)&Bs[srow][sc] = b0; *(uint4*)&Bs[srow][sc + 8] = b1;
    __syncthreads();
    const int ml = (w << 4) + (lane & 15);
    const int kq = (lane >> 4) << 3;
    short8 aF0 = *(short8*)&As[ml][kq];
    short8 aF1 = *(short8*)&As[ml][kq + 32];
#pragma unroll
    for (int nt = 0; nt < 4; ++nt) {
      const int nl = (nt << 4) + (lane & 15);
      short8 bF0 = *(short8*)&Bs[nl][kq];
      short8 bF1 = *(short8*)&Bs[nl][kq + 32];
      acc[nt] = __builtin_amdgcn_mfma_f32_16x16x32_bf16(aF0, bF0, acc[nt], 0, 0, 0);
      acc[nt] = __builtin_amdgcn_mfma_f32_16x16x32_bf16(aF1, bF1, acc[nt], 0, 0, 0);
    }
  }
#pragma unroll
  for (int nt = 0; nt < 4; ++nt) {
    int col = n0 + (nt << 4) + (lane & 15);
#pragma unroll
    for (int r = 0; r < 4; ++r) {
      int row = m0 + (w << 4) + ((lane >> 4) << 2) + r;
      out[row * 512 + col] = acc[nt][r];
    }
  }
}

// ---------------- Pwh[h][delta+511][d] table (fp16) ----------------
__global__ __launch_bounds__(256) void build_pw(const float* __restrict__ P,
                                                const float* __restrict__ sigma,
                                                unsigned short* __restrict__ Pwh) {
  int idx = blockIdx.x * blockDim.x + threadIdx.x;
  if (idx >= Hh * 1023 * 64) return;
  int d = idx & 63;
  int rem = idx >> 6;
  int dd = rem % 1023;
  int h = rem / 1023;
  float s = fabsf(sigma[h]) + 1e-6f;
  float delta = (float)(dd - 511);
  float dt = 128.0f * tanhf(delta / s) + 128.0f;
  float lo = floorf(dt);
  int ilo = (int)lo;
  float frac = dt - lo;
  ilo = max(0, min(ilo, 256));
  int ihi = min(ilo + 1, 256);
  const float* Pb = P + h * 257 * 64;
  float val = (1.0f - frac) * Pb[ilo * 64 + d] + frac * Pb[ihi * 64 + d];
  __fp16 hv = (__fp16)val;
  Pwh[idx] = *(unsigned short*)&hv;
}

// ---------------- Attention v7: fp16 sources, copy-only staging, heavy-first ----------------
// grid (B*H=64, T/32=16); i0 = 480 - 32*by so heavy (9-j-tile) blocks dispatch first.
// All inputs pre-converted fp16 (qh/kh normalized, vhu row-paired, Pwh table) ->
// staging is pure b128 copies, zero cvt in the j-loop.
__global__ __launch_bounds__(256) void attn(
    const unsigned short* __restrict__ qh, const unsigned short* __restrict__ kh,
    const unsigned* __restrict__ vhu, const unsigned short* __restrict__ Pwh,
    unsigned short* __restrict__ yb) {
  __shared__ __fp16 Ks[64][72];
  __shared__ __fp16 PwS[96][72];
  __shared__ __fp16 qS[32][72];
  __shared__ __fp16 pS[4][32][16];

  const int t = threadIdx.x;
  const int w = t >> 6;
  const int lane = t & 63;
  const int bh = blockIdx.x;
  const int b = bh >> 3;
  const int h = bh & 7;
  const int hkv = h >> 1;
  const int i0 = 480 - blockIdx.y * 32;  // heavy blocks first

  // stage q tile (32 rows x 64 fp16): thread t -> row t>>3, 8 elems at (t&7)*8
  {
    int row = t >> 3, dc = (t & 7) << 3;
    *(uint4*)&qS[row][dc] =
        *(const uint4*)&qh[((b * Tt + i0 + row) * Hh + h) * Dd + dc];
  }

  float m_run[8], l_run[8], o_run[8];
#pragma unroll
  for (int r = 0; r < 8; ++r) { m_run[r] = -1e30f; l_run[r] = 0.0f; o_run[r] = 0.0f; }

  const int prow = (w << 3) + 63 - lane;
  const int i_base = i0 + (w << 3);

  for (int jt0 = 0; jt0 <= i0 + 31; jt0 += 64) {
    __syncthreads();
    {
      // K rows 0..63 + PwS rows 0..63: thread t -> row t>>2, 16 elems at (t&3)*16
      int jr = t >> 2, dc = (t & 3) << 4;
      const unsigned short* kp = &kh[((b * Tt + jt0 + jr) * HKV + hkv) * Dd + dc];
      *(uint4*)&Ks[jr][dc]     = *(const uint4*)&kp[0];
      *(uint4*)&Ks[jr][dc + 8] = *(const uint4*)&kp[8];

      const int pb0 = h * 1023 + (i0 - jt0) + 448;
      const unsigned short* pwp = &Pwh[(pb0 + jr) * 64 + dc];
      *(uint4*)&PwS[jr][dc]     = *(const uint4*)&pwp[0];
      *(uint4*)&PwS[jr][dc + 8] = *(const uint4*)&pwp[8];

      // PwS rows 64..94: thread t -> row 64+(t>>3), 8 elems at (t&7)*8
      int pr2 = 64 + (t >> 3), dc2 = (t & 7) << 3;
      if (pr2 < 95)
        *(uint4*)&PwS[pr2][dc2] = *(const uint4*)&Pwh[(pb0 + pr2) * 64 + dc2];
    }
    __syncthreads();

    // ---- score phase: lane = j; fp16 pk_mul + fdot2, fp32 accumulation ----
    float s[8];
#pragma unroll
    for (int r = 0; r < 8; ++r) s[r] = 0.0f;
#pragma unroll
    for (int ch = 0; ch < 8; ++ch) {
      const int dc = ch << 3;
      uint4 ku = *(uint4*)&Ks[lane][dc];
      h2 k0 = u2h(ku.x), k1 = u2h(ku.y), k2 = u2h(ku.z), k3 = u2h(ku.w);
#pragma unroll
      for (int r = 0; r < 8; ++r) {
        uint4 qu = *(uint4*)&qS[(w << 3) + r][dc];     // wave-uniform broadcast
        uint4 pu = *(uint4*)&PwS[prow + r][dc];
        s[r] = fdot2(u2h(qu.x) * u2h(pu.x), k0, s[r]);
        s[r] = fdot2(u2h(qu.y) * u2h(pu.y), k1, s[r]);
        s[r] = fdot2(u2h(qu.z) * u2h(pu.z), k2, s[r]);
        s[r] = fdot2(u2h(qu.w) * u2h(pu.w), k3, s[r]);
      }
    }
    const int j = jt0 + lane;
    float pv[8];
#pragma unroll
    for (int r = 0; r < 8; ++r) {
      const int i_r = i_base + r;
      float sv = (j <= i_r) ? s[r] * 0.125f : -1e30f;
      float mnew = fmaxf(m_run[r], wave_reduce_max(sv));
      float p = __expf(sv - mnew);
      float alpha = __expf(m_run[r] - mnew);
      l_run[r] = l_run[r] * alpha + wave_reduce_sum(p);
      m_run[r] = mnew;
      pv[r] = p;
      o_run[r] *= alpha;
    }
    // transpose p to fp16 j-pairs: lanes (2m,2m+1) -> pS[w][m][2r..2r+1]
    {
      unsigned u[8];
#pragma unroll
      for (int r = 0; r < 8; ++r) {
        float other = __shfl_xor(pv[r], 1, 64);
        u[r] = h2u(__builtin_amdgcn_cvt_pkrtz(pv[r], other));
      }
      if (!(lane & 1)) {
        *(uint4*)&pS[w][lane >> 1][0] = *(uint4*)&u[0];
        *(uint4*)&pS[w][lane >> 1][8] = *(uint4*)&u[4];
      }
    }

    // ---- PV phase: lane = d; fdot2 over j-pairs, paired-fp16 V from global ----
    const unsigned* vp = &vhu[(((b * Tt + jt0) >> 1) * HKV + hkv) * Dd + lane];
#pragma unroll 4
    for (int j2 = 0; j2 < 32; ++j2) {
      uint4 p0 = *(uint4*)&pS[w][j2][0];   // broadcast
      uint4 p1 = *(uint4*)&pS[w][j2][8];
      h2 vv = u2h(vp[j2 * (HKV * Dd)]);
      o_run[0] = fdot2(u2h(p0.x), vv, o_run[0]);
      o_run[1] = fdot2(u2h(p0.y), vv, o_run[1]);
      o_run[2] = fdot2(u2h(p0.z), vv, o_run[2]);
      o_run[3] = fdot2(u2h(p0.w), vv, o_run[3]);
      o_run[4] = fdot2(u2h(p1.x), vv, o_run[4]);
      o_run[5] = fdot2(u2h(p1.y), vv, o_run[5]);
      o_run[6] = fdot2(u2h(p1.z), vv, o_run[6]);
      o_run[7] = fdot2(u2h(p1.w), vv, o_run[7]);
    }
  }
#pragma unroll
  for (int r = 0; r < 8; ++r) {
    const int i_r = i_base + r;
    __hip_bfloat16 hv = __float2bfloat16(o_run[r] / l_run[r]);
    yb[((b * Tt + i_r) * Hh + h) * Dd + lane] = *(unsigned short*)&hv;
  }
}

extern "C" void kernel_launch(void* const* d_in, const int* in_sizes, int n_in,
                              void* d_out, int out_size, void* d_ws, size_t ws_size,
                              hipStream_t stream) {
  const float* x     = (const float*)d_in[0];
  const float* Wq    = (const float*)d_in[1];
  const float* Wk    = (const float*)d_in[2];
  const float* Wv    = (const float*)d_in[3];
  const float* Wproj = (const float*)d_in[4];
  const float* P     = (const float*)d_in[5];
  const float* sigma = (const float*)d_in[6];
  float* out = (float*)d_out;

  float* ws = (float*)d_ws;
  unsigned short* qh  = (unsigned short*)ws;                // 2,097,152 h = 1,048,576 f
  unsigned short* kh  = (unsigned short*)(ws + 1048576);    // 1,048,576 h = 524,288 f
  unsigned*       vhu = (unsigned*)(ws + 1572864);          // 524,288 u = 524,288 f
  unsigned short* Pwh = (unsigned short*)(ws + 2097152);    // 523,776 h -> 262,144 f
  unsigned short* xb  = (unsigned short*)(ws + 2359296);    // 2M bf16 = 1,048,576 f
  unsigned short* yb  = xb;                                 // alias: xb dead after qkv_mfma
  unsigned short* Wtq = (unsigned short*)(ws + 3407872);    // 524,288 h = 262,144 f
  unsigned short* Wtp = (unsigned short*)(ws + 3670016);    // 262,144 h = 131,072 f
  // total 3,801,088 floats = 15.2 MB

  conv_x<<<dim3(1024), 256, 0, stream>>>(x, xb);
  conv_w<<<dim3(8, 24), 256, 0, stream>>>(Wq, Wk, Wv, Wproj, Wtq, Wtp);
  qkv_mfma<<<dim3(64, 16), 256, 0, stream>>>(xb, Wtq, qh, kh, vhu);
  build_pw<<<dim3(2046), 256, 0, stream>>>(P, sigma, Pwh);
  attn<<<dim3(64, 16), 256, 0, stream>>>(qh, kh, vhu, Pwh, yb);
  proj_mfma<<<dim3(64, 8), 256, 0, stream>>>(yb, Wtp, out);
}

// Round 9
// 157.702 us; speedup vs baseline: 4.1221x; 1.0608x over previous
//
#include <hip/hip_runtime.h>
#include <hip/hip_bf16.h>
#include <math.h>

#define Bb 8
#define Tt 512
#define Cc 512
#define Hh 8
#define HKV 4
#define Dd 64

typedef __attribute__((ext_vector_type(8))) short short8;
typedef __attribute__((ext_vector_type(4))) float float4v;
typedef __attribute__((ext_vector_type(2))) __fp16 h2;  // matches cvt_pkrtz return type

__device__ __forceinline__ h2 u2h(unsigned u) {
  union { unsigned u; h2 h; } x; x.u = u; return x.h;
}
__device__ __forceinline__ unsigned h2u(h2 h) {
  union { h2 h; unsigned u; } x; x.h = h; return x.u;
}
__device__ __forceinline__ float fdot2(h2 a, h2 b, float c) {
#if __has_builtin(__builtin_amdgcn_fdot2)
  return __builtin_amdgcn_fdot2(a, b, c, false);
#else
  return fmaf((float)a.x, (float)b.x, fmaf((float)a.y, (float)b.y, c));
#endif
}

__device__ __forceinline__ float wave_reduce_sum(float v) {
#pragma unroll
  for (int off = 32; off > 0; off >>= 1) v += __shfl_xor(v, off, 64);
  return v;
}
__device__ __forceinline__ unsigned pack_bf2(float a, float b) {
  __hip_bfloat162 h = __float22bfloat162_rn(make_float2(a, b));
  return *(unsigned*)&h;
}

// ---------------- x fp32 -> bf16 ----------------
__global__ __launch_bounds__(256) void conv_x(const float* __restrict__ x,
                                              unsigned short* __restrict__ xb) {
  int i = (blockIdx.x * 256 + threadIdx.x) * 8;
  float4 f0 = *(const float4*)&x[i];
  float4 f1 = *(const float4*)&x[i + 4];
  unsigned u[4] = {pack_bf2(f0.x, f0.y), pack_bf2(f0.z, f0.w),
                   pack_bf2(f1.x, f1.y), pack_bf2(f1.z, f1.w)};
  *(uint4*)&xb[i] = *(uint4*)u;
}

// ---------------- W transpose+convert: Wt[n][k] bf16 ----------------
__global__ __launch_bounds__(256) void conv_w(
    const float* __restrict__ Wq, const float* __restrict__ Wk,
    const float* __restrict__ Wv, const float* __restrict__ Wp,
    unsigned short* __restrict__ Wtq, unsigned short* __restrict__ Wtp) {
  __shared__ float Ts[64][65];
  const int k0 = blockIdx.x * 64;
  const int n0 = blockIdx.y * 64;
  const float* src; int ld, nc0; unsigned short* dst; int ndst;
  if (n0 < 512)       { src = Wq; ld = 512; nc0 = n0;        dst = Wtq; ndst = n0; }
  else if (n0 < 768)  { src = Wk; ld = 256; nc0 = n0 - 512;  dst = Wtq; ndst = n0; }
  else if (n0 < 1024) { src = Wv; ld = 256; nc0 = n0 - 768;  dst = Wtq; ndst = n0; }
  else                { src = Wp; ld = 512; nc0 = n0 - 1024; dst = Wtp; ndst = n0 - 1024; }
  const int t = threadIdx.x;
  const int r = t >> 4, c4 = (t & 15) << 2;
#pragma unroll
  for (int rr = 0; rr < 4; ++rr) {
    int row = (rr << 4) + r;
    float4 f = *(const float4*)&src[(k0 + row) * ld + nc0 + c4];
    Ts[row][c4] = f.x; Ts[row][c4 + 1] = f.y;
    Ts[row][c4 + 2] = f.z; Ts[row][c4 + 3] = f.w;
  }
  __syncthreads();
#pragma unroll
  for (int rr = 0; rr < 4; ++rr) {
    int nr = (rr << 4) + r;
    unsigned u0 = pack_bf2(Ts[c4][nr], Ts[c4 + 1][nr]);
    unsigned u1 = pack_bf2(Ts[c4 + 2][nr], Ts[c4 + 3][nr]);
    *(uint2*)&dst[(ndst + nr) * 512 + k0 + c4] = make_uint2(u0, u1);
  }
}

// ---------------- QKV MFMA GEMM + fused RMS-norm + fp16 emit ----------------
__global__ __launch_bounds__(256) void qkv_mfma(
    const unsigned short* __restrict__ xb, const unsigned short* __restrict__ Wt,
    unsigned short* __restrict__ qh, unsigned short* __restrict__ kh,
    unsigned* __restrict__ vhu) {
  __shared__ unsigned short As[64][64];
  __shared__ unsigned short Bs[64][64];
  const int m0 = blockIdx.x * 64;
  const int n0 = blockIdx.y * 64;
  const int t = threadIdx.x;
  const int w = t >> 6, lane = t & 63;
  const int srow = t >> 2, sc = (t & 3) << 4;
  float4v acc[4] = {{0,0,0,0},{0,0,0,0},{0,0,0,0},{0,0,0,0}};
  for (int k0 = 0; k0 < 512; k0 += 64) {
    uint4 a0 = *(const uint4*)&xb[(m0 + srow) * 512 + k0 + sc];
    uint4 a1 = *(const uint4*)&xb[(m0 + srow) * 512 + k0 + sc + 8];
    uint4 b0 = *(const uint4*)&Wt[(n0 + srow) * 512 + k0 + sc];
    uint4 b1 = *(const uint4*)&Wt[(n0 + srow) * 512 + k0 + sc + 8];
    __syncthreads();
    *(uint4*)&As[srow][sc] = a0; *(uint4*)&As[srow][sc + 8] = a1;
    *(uint4*)&Bs[srow][sc] = b0; *(uint4*)&Bs[srow][sc + 8] = b1;
    __syncthreads();
    const int ml = (w << 4) + (lane & 15);
    const int kq = (lane >> 4) << 3;
    short8 aF0 = *(short8*)&As[ml][kq];
    short8 aF1 = *(short8*)&As[ml][kq + 32];
#pragma unroll
    for (int nt = 0; nt < 4; ++nt) {
      const int nl = (nt << 4) + (lane & 15);
      short8 bF0 = *(short8*)&Bs[nl][kq];
      short8 bF1 = *(short8*)&Bs[nl][kq + 32];
      acc[nt] = __builtin_amdgcn_mfma_f32_16x16x32_bf16(aF0, bF0, acc[nt], 0, 0, 0);
      acc[nt] = __builtin_amdgcn_mfma_f32_16x16x32_bf16(aF1, bF1, acc[nt], 0, 0, 0);
    }
  }
  const int lane15 = lane & 15;
  const int rowbase = m0 + (w << 4) + ((lane >> 4) << 2);
  if (n0 < 768) {
#pragma unroll
    for (int r = 0; r < 4; ++r) {
      float ss = 0.0f;
#pragma unroll
      for (int nt = 0; nt < 4; ++nt) ss = fmaf(acc[nt][r], acc[nt][r], ss);
#pragma unroll
      for (int off = 1; off < 16; off <<= 1) ss += __shfl_xor(ss, off, 64);
      float sc2 = 8.0f * rsqrtf(ss + 1e-6f);
      const int row = rowbase + r;
      if (n0 < 512) {
        const int h = n0 >> 6;
#pragma unroll
        for (int nt = 0; nt < 4; ++nt) {
          __fp16 hv = (__fp16)(acc[nt][r] * sc2);
          qh[(row * Hh + h) * Dd + (nt << 4) + lane15] = *(unsigned short*)&hv;
        }
      } else {
        const int hkv = (n0 - 512) >> 6;
#pragma unroll
        for (int nt = 0; nt < 4; ++nt) {
          __fp16 hv = (__fp16)(acc[nt][r] * sc2);
          kh[(row * HKV + hkv) * Dd + (nt << 4) + lane15] = *(unsigned short*)&hv;
        }
      }
    }
  } else {
    const int hkv = (n0 - 768) >> 6;
#pragma unroll
    for (int r = 0; r < 4; r += 2) {
      const int rp = (rowbase + r) >> 1;
#pragma unroll
      for (int nt = 0; nt < 4; ++nt) {
        unsigned u = h2u(__builtin_amdgcn_cvt_pkrtz(acc[nt][r], acc[nt][r + 1]));
        vhu[(rp * HKV + hkv) * Dd + (nt << 4) + lane15] = u;
      }
    }
  }
}

// ---------------- Proj MFMA GEMM ----------------
__global__ __launch_bounds__(256) void proj_mfma(
    const unsigned short* __restrict__ yb, const unsigned short* __restrict__ Wt,
    float* __restrict__ out) {
  __shared__ unsigned short As[64][64];
  __shared__ unsigned short Bs[64][64];
  const int m0 = blockIdx.x * 64;
  const int n0 = blockIdx.y * 64;
  const int t = threadIdx.x;
  const int w = t >> 6, lane = t & 63;
  const int srow = t >> 2, sc = (t & 3) << 4;
  float4v acc[4] = {{0,0,0,0},{0,0,0,0},{0,0,0,0},{0,0,0,0}};
  for (int k0 = 0; k0 < 512; k0 += 64) {
    uint4 a0 = *(const uint4*)&yb[(m0 + srow) * 512 + k0 + sc];
    uint4 a1 = *(const uint4*)&yb[(m0 + srow) * 512 + k0 + sc + 8];
    uint4 b0 = *(const uint4*)&Wt[(n0 + srow) * 512 + k0 + sc];
    uint4 b1 = *(const uint4*)&Wt[(n0 + srow) * 512 + k0 + sc + 8];
    __syncthreads();
    *(uint4*)&As[srow][sc] = a0; *(uint4*)&As[srow][sc + 8] = a1;
    *(uint4*)&Bs[srow][sc] = b0; *(uint4*)&Bs[srow][sc + 8] = b1;
    __syncthreads();
    const int ml = (w << 4) + (lane & 15);
    const int kq = (lane >> 4) << 3;
    short8 aF0 = *(short8*)&As[ml][kq];
    short8 aF1 = *(short8*)&As[ml][kq + 32];
#pragma unroll
    for (int nt = 0; nt < 4; ++nt) {
      const int nl = (nt << 4) + (lane & 15);
      short8 bF0 = *(short8*)&Bs[nl][kq];
      short8 bF1 = *(short8*)&Bs[nl][kq + 32];
      acc[nt] = __builtin_amdgcn_mfma_f32_16x16x32_bf16(aF0, bF0, acc[nt], 0, 0, 0);
      acc[nt] = __builtin_amdgcn_mfma_f32_16x16x32_bf16(aF1, bF1, acc[nt], 0, 0, 0);
    }
  }
#pragma unroll
  for (int nt = 0; nt < 4; ++nt) {
    int col = n0 + (nt << 4) + (lane & 15);
#pragma unroll
    for (int r = 0; r < 4; ++r) {
      int row = m0 + (w << 4) + ((lane >> 4) << 2) + r;
      out[row * 512 + col] = acc[nt][r];
    }
  }
}

// ---------------- Pwh[h][delta+511][d] table (fp16) ----------------
__global__ __launch_bounds__(256) void build_pw(const float* __restrict__ P,
                                                const float* __restrict__ sigma,
                                                unsigned short* __restrict__ Pwh) {
  int idx = blockIdx.x * blockDim.x + threadIdx.x;
  if (idx >= Hh * 1023 * 64) return;
  int d = idx & 63;
  int rem = idx >> 6;
  int dd = rem % 1023;
  int h = rem / 1023;
  float s = fabsf(sigma[h]) + 1e-6f;
  float delta = (float)(dd - 511);
  float dt = 128.0f * tanhf(delta / s) + 128.0f;
  float lo = floorf(dt);
  int ilo = (int)lo;
  float frac = dt - lo;
  ilo = max(0, min(ilo, 256));
  int ihi = min(ilo + 1, 256);
  const float* Pb = P + h * 257 * 64;
  float val = (1.0f - frac) * Pb[ilo * 64 + d] + frac * Pb[ihi * 64 + d];
  __fp16 hv = (__fp16)val;
  Pwh[idx] = *(unsigned short*)&hv;
}

// ---------------- Attention v8: fixed-shift softmax, q/K off the LDS pipe ----------------
// grid (B*H=64, T/32=16); i0 = 480 - 32*by (heavy blocks first); 4 waves x 8 rows.
// |sv| <= 8 by Cauchy-Schwarz (||q||=||k||=8, |Pw|<=1) -> fixed shift m=6:
//   p = exp(sv-6) is exact softmax (shift cancels in o/l), no per-tile wave-reduce,
//   no alpha-rescale. l accumulated per-lane, reduced ONCE at the end.
// q rows: wave-uniform -> global broadcast loads (readfirstlane-forced uniform).
// K row per lane -> 8 uint4 regs from global (L2-hot). LDS: PwS + pS only (17.9KB).
__global__ __launch_bounds__(256) void attn(
    const unsigned short* __restrict__ qh, const unsigned short* __restrict__ kh,
    const unsigned* __restrict__ vhu, const unsigned short* __restrict__ Pwh,
    unsigned short* __restrict__ yb) {
  __shared__ __fp16 PwS[96][72];
  __shared__ __fp16 pS[4][32][16];

  const int t = threadIdx.x;
  const int lane = t & 63;
  const int wu = __builtin_amdgcn_readfirstlane(t >> 6);  // uniform wave id
  const int bh = blockIdx.x;
  const int b = bh >> 3;
  const int h = bh & 7;
  const int hkv = h >> 1;
  const int i0 = 480 - blockIdx.y * 32;  // heavy blocks first

  float l_lane[8], o_run[8];
#pragma unroll
  for (int r = 0; r < 8; ++r) { l_lane[r] = 0.0f; o_run[r] = 0.0f; }

  const int prow = (wu << 3) + 63 - lane;
  const int i_base = i0 + (wu << 3);
  const unsigned short* qbase = &qh[((b * Tt + i_base) * Hh + h) * Dd];

  for (int jt0 = 0; jt0 <= i0 + 31; jt0 += 64) {
    __syncthreads();
    {
      // PwS rows 0..63: thread t -> row t>>2, 16 elems at (t&3)*16
      int jr = t >> 2, dc = (t & 3) << 4;
      const int pb0 = h * 1023 + (i0 - jt0) + 448;
      const unsigned short* pwp = &Pwh[(pb0 + jr) * 64 + dc];
      *(uint4*)&PwS[jr][dc]     = *(const uint4*)&pwp[0];
      *(uint4*)&PwS[jr][dc + 8] = *(const uint4*)&pwp[8];
      // PwS rows 64..94: thread t -> row 64+(t>>3), 8 elems at (t&7)*8
      int pr2 = 64 + (t >> 3), dc2 = (t & 7) << 3;
      if (pr2 < 95)
        *(uint4*)&PwS[pr2][dc2] = *(const uint4*)&Pwh[(pb0 + pr2) * 64 + dc2];
    }
    // K row for this lane -> 8 uint4 regs (global, L2-hot; off the LDS pipe)
    uint4 kr[8];
    {
      const uint4* kp = (const uint4*)&kh[((b * Tt + jt0 + lane) * HKV + hkv) * Dd];
#pragma unroll
      for (int c = 0; c < 8; ++c) kr[c] = kp[c];
    }
    __syncthreads();

    // ---- score phase: lane = j; q broadcast from global, Pw from LDS, K regs ----
    const int j = jt0 + lane;
    float pv8[8];
#pragma unroll
    for (int r = 0; r < 8; ++r) {
      const uint4* qp = (const uint4*)&qbase[r * (Hh * Dd)];  // wave-uniform
      float sr = 0.0f;
#pragma unroll
      for (int ch = 0; ch < 8; ++ch) {
        uint4 qu = qp[ch];
        uint4 pu = *(uint4*)&PwS[prow + r][ch << 3];
        sr = fdot2(u2h(qu.x) * u2h(pu.x), u2h(kr[ch].x), sr);
        sr = fdot2(u2h(qu.y) * u2h(pu.y), u2h(kr[ch].y), sr);
        sr = fdot2(u2h(qu.z) * u2h(pu.z), u2h(kr[ch].z), sr);
        sr = fdot2(u2h(qu.w) * u2h(pu.w), u2h(kr[ch].w), sr);
      }
      float sv = (j <= i_base + r) ? sr * 0.125f : -1e30f;
      float p = __expf(sv - 6.0f);   // fixed shift: exact softmax, no reduce
      l_lane[r] += p;
      pv8[r] = p;
    }
    // transpose p to fp16 j-pairs: lanes (2m,2m+1) -> pS[w][m][2r..2r+1]
    {
      unsigned u[8];
#pragma unroll
      for (int r = 0; r < 8; ++r) {
        float other = __shfl_xor(pv8[r], 1, 64);
        u[r] = h2u(__builtin_amdgcn_cvt_pkrtz(pv8[r], other));
      }
      if (!(lane & 1)) {
        *(uint4*)&pS[wu][lane >> 1][0] = *(uint4*)&u[0];
        *(uint4*)&pS[wu][lane >> 1][8] = *(uint4*)&u[4];
      }
    }

    // ---- PV phase: lane = d; fdot2 over j-pairs, paired-fp16 V from global ----
    const unsigned* vp = &vhu[(((b * Tt + jt0) >> 1) * HKV + hkv) * Dd + lane];
#pragma unroll 4
    for (int j2 = 0; j2 < 32; ++j2) {
      uint4 p0 = *(uint4*)&pS[wu][j2][0];   // broadcast
      uint4 p1 = *(uint4*)&pS[wu][j2][8];
      h2 vv = u2h(vp[j2 * (HKV * Dd)]);
      o_run[0] = fdot2(u2h(p0.x), vv, o_run[0]);
      o_run[1] = fdot2(u2h(p0.y), vv, o_run[1]);
      o_run[2] = fdot2(u2h(p0.z), vv, o_run[2]);
      o_run[3] = fdot2(u2h(p0.w), vv, o_run[3]);
      o_run[4] = fdot2(u2h(p1.x), vv, o_run[4]);
      o_run[5] = fdot2(u2h(p1.y), vv, o_run[5]);
      o_run[6] = fdot2(u2h(p1.z), vv, o_run[6]);
      o_run[7] = fdot2(u2h(p1.w), vv, o_run[7]);
    }
  }
  // single final reduce for l, then write
#pragma unroll
  for (int r = 0; r < 8; ++r) {
    float l = wave_reduce_sum(l_lane[r]);
    const int i_r = i_base + r;
    __hip_bfloat16 hv = __float2bfloat16(o_run[r] / l);
    yb[((b * Tt + i_r) * Hh + h) * Dd + lane] = *(unsigned short*)&hv;
  }
}

extern "C" void kernel_launch(void* const* d_in, const int* in_sizes, int n_in,
                              void* d_out, int out_size, void* d_ws, size_t ws_size,
                              hipStream_t stream) {
  const float* x     = (const float*)d_in[0];
  const float* Wq    = (const float*)d_in[1];
  const float* Wk    = (const float*)d_in[2];
  const float* Wv    = (const float*)d_in[3];
  const float* Wproj = (const float*)d_in[4];
  const float* P     = (const float*)d_in[5];
  const float* sigma = (const float*)d_in[6];
  float* out = (float*)d_out;

  float* ws = (float*)d_ws;
  unsigned short* qh  = (unsigned short*)ws;                // 2,097,152 h = 1,048,576 f
  unsigned short* kh  = (unsigned short*)(ws + 1048576);    // 1,048,576 h = 524,288 f
  unsigned*       vhu = (unsigned*)(ws + 1572864);          // 524,288 u = 524,288 f
  unsigned short* Pwh = (unsigned short*)(ws + 2097152);    // 523,776 h -> 262,144 f
  unsigned short* xb  = (unsigned short*)(ws + 2359296);    // 2M bf16 = 1,048,576 f
  unsigned short* yb  = xb;                                 // alias: xb dead after qkv_mfma
  unsigned short* Wtq = (unsigned short*)(ws + 3407872);    // 524,288 h = 262,144 f
  unsigned short* Wtp = (unsigned short*)(ws + 3670016);    // 262,144 h = 131,072 f

  conv_x<<<dim3(1024), 256, 0, stream>>>(x, xb);
  conv_w<<<dim3(8, 24), 256, 0, stream>>>(Wq, Wk, Wv, Wproj, Wtq, Wtp);
  qkv_mfma<<<dim3(64, 16), 256, 0, stream>>>(xb, Wtq, qh, kh, vhu);
  build_pw<<<dim3(2046), 256, 0, stream>>>(P, sigma, Pwh);
  attn<<<dim3(64, 16), 256, 0, stream>>>(qh, kh, vhu, Pwh, yb);
  proj_mfma<<<dim3(64, 8), 256, 0, stream>>>(yb, Wtp, out);
}